// Round 5
// baseline (255.583 us; speedup 1.0000x reference)
//
#include <hip/hip_runtime.h>
#include <math.h>

#define N_NODES 10000
#define N_EDGES 160000
#define D 256
#define H1 8
#define CH 32
#define TDIM 128
#define MSGD 128
#define RT1 157      // ceil(10000/64)
#define RTE 2500     // 160000/64

static inline int ceildiv(int a, int b) { return (a + b - 1) / b; }

typedef float f32x4 __attribute__((ext_vector_type(4)));
typedef short bf16x8 __attribute__((ext_vector_type(8)));

__device__ __forceinline__ unsigned short f2bf(float f) {
  unsigned int u = __builtin_bit_cast(unsigned int, f);
  u += 0x7FFFu + ((u >> 16) & 1u);   // RNE
  return (unsigned short)(u >> 16);
}
__device__ __forceinline__ float bf2f(unsigned short h) {
  unsigned int u = ((unsigned int)h) << 16;
  return __builtin_bit_cast(float, u);
}

// ---------------- prep ----------------
__global__ void count_kernel(const int* __restrict__ dstp, int* __restrict__ deg, int E) {
  for (int i = blockIdx.x * blockDim.x + threadIdx.x; i < E; i += gridDim.x * blockDim.x)
    atomicAdd(&deg[dstp[i]], 1);
}

// 1024 threads, each owns 10 contiguous elements; ~20 barriers total
__global__ void scan_kernel(const int* __restrict__ deg, int* __restrict__ rowptr, int n) {
  __shared__ int part[1024];
  const int tid = threadIdx.x;
  const int CHK = 10;
  int base = tid * CHK;
  int loc[CHK];
  int s = 0;
#pragma unroll
  for (int j = 0; j < CHK; ++j) {
    int idx = base + j;
    int v = (idx < n) ? deg[idx] : 0;
    loc[j] = s; s += v;
  }
  part[tid] = s;
  __syncthreads();
  for (int off = 1; off < 1024; off <<= 1) {
    int y = (tid >= off) ? part[tid - off] : 0;
    __syncthreads();
    part[tid] += y;
    __syncthreads();
  }
  int pre = tid ? part[tid - 1] : 0;
#pragma unroll
  for (int j = 0; j < CHK; ++j) {
    int idx = base + j;
    if (idx < n) rowptr[idx] = pre + loc[j];
  }
  if (tid == 1023) rowptr[n] = part[1023];
}

__global__ void scatter_kernel(const int* __restrict__ dstp, const int* __restrict__ rowptr,
                               int* __restrict__ fill, int* __restrict__ eid, int E) {
  for (int e = blockIdx.x * blockDim.x + threadIdx.x; e < E; e += gridDim.x * blockDim.x) {
    int d = dstp[e];
    int pos = atomicAdd(&fill[d], 1);
    eid[rowptr[d] + pos] = e;
  }
}

// sorted rel_t + sorted src
__global__ void relsort_kernel(const float* __restrict__ lu, const int* __restrict__ srcp,
                               const float* __restrict__ tt, const int* __restrict__ eid,
                               float* __restrict__ rel_s, int* __restrict__ srcs, int E) {
  for (int i = blockIdx.x * blockDim.x + threadIdx.x; i < E; i += gridDim.x * blockDim.x) {
    int e = eid[i];
    int s = srcp[e];
    srcs[i] = s;
    rel_s[i] = lu[s] - tt[e];
  }
}

// msg gathered to SORTED order, bf16, A-frag layout (the msg half: ks 0..3 of 4)
// read side coalesced (512B contiguous per edge row); barrier-free, latency via TLP
__global__ void msg_gather_kernel(const float* __restrict__ msg, const int* __restrict__ eid,
                                  unsigned short* __restrict__ msgf) {
  int t = blockIdx.x * blockDim.x + threadIdx.x;
  if (t >= N_EDGES * 16) return;
  int i = t >> 4, kc = t & 15;
  int e = eid[i];
  const float4* pm = (const float4*)(msg + (size_t)e * MSGD + kc * 8);
  float4 f0 = pm[0], f1 = pm[1];
  union { uint4 q; unsigned short s[8]; } u;
  u.s[0]=f2bf(f0.x); u.s[1]=f2bf(f0.y); u.s[2]=f2bf(f0.z); u.s[3]=f2bf(f0.w);
  u.s[4]=f2bf(f1.x); u.s[5]=f2bf(f1.y); u.s[6]=f2bf(f1.z); u.s[7]=f2bf(f1.w);
  int rt=i>>6, rf=(i>>4)&3, ir=i&15, ks=kc>>2, kg=kc&3;
  *(uint4*)&msgf[(size_t)rt*8192 + ks*2048 + rf*512 + (ir+16*kg)*8] = u.q;
}

// ---------------- operand-layout converters ----------------
// A frag layout (ushorts): addr(i,k) = rt*16384 + ks*2048 + rf*512 + (ir+16*kg)*8 + j
//   rt=i>>6, rf=(i>>4)&3, ir=i&15 ; ks=k>>5, kg=(k>>3)&3, j=k&7
//   NOTE: for fixed (rt,ks), 16B-chunk index == c (0..255) — linear.
// B frag layout: addr(k,c) = (ks*NFtot + (c>>4))*512 + ((c&15)+16*kg)*8 + j

__global__ void conv_x_kernel(const float* __restrict__ x, unsigned short* __restrict__ xa,
                              int M, int RT) {
  int t = blockIdx.x * blockDim.x + threadIdx.x;
  if (t >= RT * 64 * 32) return;
  int i = t >> 5, k8 = t & 31;
  int k = k8 * 8;
  union { uint4 q; unsigned short s[8]; } u;
  if (i < M) {
    const float4* px = (const float4*)(x + (size_t)i * 256 + k);
    float4 f0 = px[0], f1 = px[1];
    u.s[0]=f2bf(f0.x); u.s[1]=f2bf(f0.y); u.s[2]=f2bf(f0.z); u.s[3]=f2bf(f0.w);
    u.s[4]=f2bf(f1.x); u.s[5]=f2bf(f1.y); u.s[6]=f2bf(f1.z); u.s[7]=f2bf(f1.w);
  } else {
    u.q = make_uint4(0,0,0,0);
  }
  int rt=i>>6, rf=(i>>4)&3, ir=i&15, ks=k8>>2, kg=k8&3;
  *(uint4*)&xa[(size_t)rt*16384 + ks*2048 + rf*512 + (ir+16*kg)*8] = u.q;
}

__device__ __forceinline__ void wstore(const float* __restrict__ W, unsigned short* __restrict__ out,
                                       int Nin, int n_off, int NFtot, int k, int c) {
  int gc = n_off + c;
  int ks=k>>5, kg=(k>>3)&3, j=k&7, nf=gc>>4, ic=gc&15;
  out[(size_t)(ks*NFtot+nf)*512 + (ic+16*kg)*8 + j] = f2bf(W[(size_t)k*Nin + c]);
}

__global__ void conv_all_kernel(const float* Wq1, const float* Wk1, const float* Wv1, const float* Ws1,
                                const float* We1, const float* Wq2, const float* Wk2, const float* Wv2,
                                const float* Ws2, const float* We2,
                                const float* bq1, const float* bk1, const float* bv1, const float* bs1,
                                const float* bq2, const float* bk2, const float* bv2, const float* bs2,
                                unsigned short* W1f, unsigned short* We1f, unsigned short* W2f,
                                unsigned short* We2f, float* bcat1, float* bcat2) {
  int t = blockIdx.x * blockDim.x + threadIdx.x;
  if (t < 262144) {               // W1f: 4 x 256x256
    int w = t >> 16, r = t & 65535, k = r >> 8, c = r & 255;
    const float* W = (w == 0) ? Wq1 : (w == 1) ? Wk1 : (w == 2) ? Wv1 : Ws1;
    wstore(W, W1f, 256, w * 256, 64, k, c);
  } else if (t < 327680) {        // We1f: 256x256
    int r = t - 262144, k = r >> 8, c = r & 255;
    wstore(We1, We1f, 256, 0, 16, k, c);
  } else if (t < 360448) {        // W2f: 4 x 256x32
    int r = t - 327680, w = r >> 13, r2 = r & 8191, k = r2 >> 5, c = r2 & 31;
    const float* W = (w == 0) ? Wq2 : (w == 1) ? Wk2 : (w == 2) ? Wv2 : Ws2;
    wstore(W, W2f, 32, w * 32, 8, k, c);
  } else if (t < 368640) {        // We2f: 256x32 (cols 32-63 pre-zeroed)
    int r = t - 360448, k = r >> 5, c = r & 31;
    wstore(We2, We2f, 32, 0, 4, k, c);
  } else if (t < 369792) {        // biases
    int r = t - 368640;
    if (r < 1024) {
      const float* b = (r < 256) ? bq1 : (r < 512) ? bk1 : (r < 768) ? bv1 : bs1;
      bcat1[r] = b[r & 255];
    } else {
      int r2 = r - 1024;
      const float* b = (r2 < 32) ? bq2 : (r2 < 64) ? bk2 : (r2 < 96) ? bv2 : bs2;
      bcat2[r2] = b[r2 & 31];
    }
  }
}

// ---------------- MFMA GEMM ----------------
// Wave tile 64x64 (4x4 frags), 4 waves/block. K=256 (8 K-steps of 32), K-order
// staggered per block (ks = ksi ^ (bx&7)) to decorrelate shared-B L2 reads.
// SYNTH: A rows synthesized: k<128 -> cos(rel*tw+tb); k>=128 -> linear read of msgf
//        (pre-gathered, sorted, frag-linear).
// EPI 0: f32 direct stores. EPI 1: bf16 via per-wave split-pass LDS (keeps LDS ~9KB).
// EPI 2: node1 quad by blockIdx.y: y0->qf f32, y1/y2->kvb bf16 (dc0 0/256), y3->sf f32.
template <int WRW, int EPI, bool SYNTH>
__global__ __launch_bounds__(256)
void gemm_mfma(const unsigned short* __restrict__ A, const unsigned short* __restrict__ B,
               const float* __restrict__ bias, void* __restrict__ C0, void* __restrict__ C1,
               void* __restrict__ C2, int RT, int M, int NFtot, int Creal, int Cstride, int dcol0,
               const float* __restrict__ rel, const float* __restrict__ tw,
               const float* __restrict__ tb, const unsigned short* __restrict__ msgf) {
  constexpr int WCW = 4 / WRW;
  constexpr int ACH = WRW * 256;
  constexpr int BCH = WCW * 256;
  constexpr int CH_TOT = ACH + BCH;
  constexpr int PER_T = CH_TOT / 256;
  constexpr int PA = ACH / 256;
  constexpr int STAGE_B = CH_TOT * 16;
  constexpr int CTILE_B = (EPI != 0) ? 64 * 72 * 2 : 0;   // per-wave split-pass buffer
  constexpr int LDS_B = (STAGE_B > CTILE_B) ? STAGE_B : CTILE_B;
  __shared__ char ldsraw[LDS_B];
  uint4* lds = (uint4*)ldsraw;

  const int tid = threadIdx.x;
  const int wid = tid >> 6, lane = tid & 63;
  const int wr = (WRW == 1) ? 0 : ((WRW == 4) ? wid : (wid >> 1));
  const int wc = (WRW == 1) ? wid : ((WRW == 4) ? 0 : (wid & 1));
  const int rt0 = blockIdx.x * WRW;
  const int n0f = blockIdx.y * (WCW * 4);
  const int phase = blockIdx.x & 7;

  auto fetchA = [&](int ks, int c) -> uint4 {
    int rt = rt0 + (c >> 8);
    if (rt >= RT) rt = RT - 1;
    if constexpr (SYNTH) {
      if (ks < 4) {
        int rem = c & 255;
        int rf = rem >> 6, r2 = rem & 63, ir = r2 & 15, kg = r2 >> 4;
        int i = rt * 64 + rf * 16 + ir;
        int k8 = ks * 4 + kg;
        float r = rel[i];
        const float4* twp = (const float4*)(tw + k8 * 8);
        const float4* tbp = (const float4*)(tb + k8 * 8);
        float4 w0 = twp[0], w1 = twp[1], b0 = tbp[0], b1 = tbp[1];
        union { uint4 q; unsigned short s[8]; } u;
        u.s[0]=f2bf(__cosf(r*w0.x+b0.x)); u.s[1]=f2bf(__cosf(r*w0.y+b0.y));
        u.s[2]=f2bf(__cosf(r*w0.z+b0.z)); u.s[3]=f2bf(__cosf(r*w0.w+b0.w));
        u.s[4]=f2bf(__cosf(r*w1.x+b1.x)); u.s[5]=f2bf(__cosf(r*w1.y+b1.y));
        u.s[6]=f2bf(__cosf(r*w1.z+b1.z)); u.s[7]=f2bf(__cosf(r*w1.w+b1.w));
        return u.q;
      } else {
        return *(const uint4*)(msgf + (size_t)rt * 8192 + (size_t)(ks - 4) * 2048 + (size_t)(c & 255) * 8);
      }
    } else {
      return *(const uint4*)(A + (size_t)rt * 16384 + (size_t)ks * 2048 + (size_t)(c & 255) * 8);
    }
  };
  auto fetchB = [&](int ks, int cb) -> uint4 {
    return *(const uint4*)(B + ((size_t)ks * NFtot + n0f) * 512 + (size_t)cb * 8);
  };

  uint4 st[PER_T];
  {
    int ks0 = 0 ^ phase;
#pragma unroll
    for (int p = 0; p < PA; ++p) st[p] = fetchA(ks0, tid + p * 256);
#pragma unroll
    for (int p = PA; p < PER_T; ++p) st[p] = fetchB(ks0, tid + (p - PA) * 256);
  }

  f32x4 acc[4][4];
#pragma unroll
  for (int i = 0; i < 4; ++i)
#pragma unroll
    for (int j = 0; j < 4; ++j) acc[i][j] = (f32x4){0.f, 0.f, 0.f, 0.f};

  for (int ksi = 0; ksi < 8; ++ksi) {
    __syncthreads();
#pragma unroll
    for (int p = 0; p < PER_T; ++p) lds[tid + p * 256] = st[p];
    if (ksi < 7) {
      int ksn = (ksi + 1) ^ phase;
#pragma unroll
      for (int p = 0; p < PA; ++p) st[p] = fetchA(ksn, tid + p * 256);
#pragma unroll
      for (int p = PA; p < PER_T; ++p) st[p] = fetchB(ksn, tid + (p - PA) * 256);
    }
    __syncthreads();
    bf16x8 a[4], b[4];
#pragma unroll
    for (int rf = 0; rf < 4; ++rf) a[rf] = *(const bf16x8*)&lds[(wr * 4 + rf) * 64 + lane];
#pragma unroll
    for (int cf = 0; cf < 4; ++cf) b[cf] = *(const bf16x8*)&lds[ACH + (wc * 4 + cf) * 64 + lane];
#pragma unroll
    for (int rf = 0; rf < 4; ++rf)
#pragma unroll
      for (int cf = 0; cf < 4; ++cf)
        acc[rf][cf] = __builtin_amdgcn_mfma_f32_16x16x32_bf16(a[rf], b[cf], acc[rf][cf], 0, 0, 0);
  }

  // ---- epilogue ----  C/D frag: col=lane&15, row=(lane>>4)*4+reg
  const int y = blockIdx.y;
  bool bf16path;
  void* dstp_; int cstr_, dc0_, bcol0_;
  if constexpr (EPI == 0) { bf16path = false; dstp_ = C0; cstr_ = Cstride; dc0_ = 0; bcol0_ = blockIdx.y * (WCW * 64); }
  else if constexpr (EPI == 1) { bf16path = true; dstp_ = C0; cstr_ = Cstride; dc0_ = dcol0; bcol0_ = 0; }
  else {
    if (y == 0)      { bf16path = false; dstp_ = C0; cstr_ = 256; dc0_ = 0;   bcol0_ = 0; }
    else if (y == 1) { bf16path = true;  dstp_ = C1; cstr_ = 512; dc0_ = 0;   bcol0_ = 256; }
    else if (y == 2) { bf16path = true;  dstp_ = C1; cstr_ = 512; dc0_ = 256; bcol0_ = 512; }
    else             { bf16path = false; dstp_ = C2; cstr_ = 256; dc0_ = 0;   bcol0_ = 768; }
  }

  if (!bf16path) {
    float* dst = (float*)dstp_;
    const int row0 = (rt0 + wr) * 64 + ((lane >> 4) * 4);
    const int cb2 = wc * 64 + (lane & 15);
#pragma unroll
    for (int cf = 0; cf < 4; ++cf) {
      int c = cb2 + cf * 16;
      if (c >= Creal) continue;
      float bv = bias ? bias[bcol0_ + c] : 0.f;
#pragma unroll
      for (int rf = 0; rf < 4; ++rf) {
#pragma unroll
        for (int j = 0; j < 4; ++j) {
          int r = row0 + rf * 16 + j;
          if (r < M) dst[(size_t)r * cstr_ + c] = acc[rf][cf][j] + bv;
        }
      }
    }
  } else {
    // split-pass: each wave in turn dumps its 64x64 sub-tile through a 9KB buffer
    unsigned short* cl = (unsigned short*)ldsraw;   // [64][72]
    unsigned short* dst = (unsigned short*)dstp_;
    const int fr0 = (lane >> 4) * 4;
    const int fc0 = lane & 15;
    const int CPCc = ((Creal < 64 ? Creal : 64) >> 3);
    const int totalc = 64 * CPCc;
    for (int pass = 0; pass < 4; ++pass) {
      __syncthreads();
      if (wid == pass) {
#pragma unroll
        for (int cf = 0; cf < 4; ++cf) {
          int c = fc0 + cf * 16;
          float bv = bias ? bias[bcol0_ + (WCW == 1 ? 0 : pass * 64) + c] : 0.f;
#pragma unroll
          for (int rf = 0; rf < 4; ++rf)
#pragma unroll
            for (int j = 0; j < 4; ++j)
              cl[(fr0 + rf * 16 + j) * 72 + c] = f2bf(acc[rf][cf][j] + bv);
        }
      }
      __syncthreads();
      for (int id = tid; id < totalc; id += 256) {
        int row = id / CPCc, cc = (id - row * CPCc) * 8;
        int gr, gcol;
        if (WCW == 1) { gr = (rt0 + pass) * 64 + row; gcol = dc0_ + cc; }
        else          { gr = rt0 * 64 + row;          gcol = dc0_ + pass * 64 + cc; }
        if (gr < M)
          *(uint4*)&dst[(size_t)gr * cstr_ + gcol] = *(const uint4*)&cl[row * 72 + cc];
      }
    }
  }
}

// ---------------- attention layer 1 (8 heads x 32, concat) ----------------
// 1 wave per dst node; lane -> (head lane>>3, 4 channels (lane&7)*4). Online softmax.
// q,s f32 [n][256]; k,v bf16 kvb[n][512] (k 0-255, v 256-511); e1b bf16 [i][256] sorted.
__global__ __launch_bounds__(64)
void attn1_kernel(const float* __restrict__ qf, const unsigned short* __restrict__ kvb,
                  const float* __restrict__ sf, const unsigned short* __restrict__ e1b,
                  const int* __restrict__ srcs, const int* __restrict__ rowptr,
                  unsigned short* __restrict__ ha) {
  const int n = blockIdx.x;
  const int lane = threadIdx.x;
  const int h = lane >> 3;
  const int c0 = (lane & 7) * 4;
  const int off = h * 32 + c0;
  const int beg = rowptr[n], end = rowptr[n + 1];
  const float4 q = *(const float4*)&qf[(size_t)n * 256 + off];
  float m = -INFINITY, den = 0.f;
  float a0 = 0.f, a1 = 0.f, a2 = 0.f, a3 = 0.f;
  for (int i = beg; i < end; ++i) {
    const int s = srcs[i];
    ushort4 ev = *(const ushort4*)&e1b[(size_t)i * 256 + off];
    ushort4 kk = *(const ushort4*)&kvb[(size_t)s * 512 + off];
    ushort4 vv = *(const ushort4*)&kvb[(size_t)s * 512 + 256 + off];
    float e0 = bf2f(ev.x), e1 = bf2f(ev.y), e2 = bf2f(ev.z), e3 = bf2f(ev.w);
    float k0 = bf2f(kk.x) + e0, k1 = bf2f(kk.y) + e1, k2 = bf2f(kk.z) + e2, k3 = bf2f(kk.w) + e3;
    float v0 = bf2f(vv.x) + e0, v1 = bf2f(vv.y) + e1, v2 = bf2f(vv.z) + e2, v3 = bf2f(vv.w) + e3;
    float p = q.x * k0 + q.y * k1 + q.z * k2 + q.w * k3;
    p += __shfl_xor(p, 1); p += __shfl_xor(p, 2); p += __shfl_xor(p, 4);
    p *= 0.17677669529663687f;   // 1/sqrt(32)
    const float mn = fmaxf(m, p);
    const float sc = __expf(m - mn);
    const float w = __expf(p - mn);
    den = den * sc + w;
    a0 = a0 * sc + w * v0; a1 = a1 * sc + w * v1;
    a2 = a2 * sc + w * v2; a3 = a3 * sc + w * v3;
    m = mn;
  }
  const float inv = 1.f / (den + 1e-16f);
  const float4 sk = *(const float4*)&sf[(size_t)n * 256 + off];
  float o0 = fmaxf(a0 * inv + sk.x, 0.f);
  float o1 = fmaxf(a1 * inv + sk.y, 0.f);
  float o2 = fmaxf(a2 * inv + sk.z, 0.f);
  float o3 = fmaxf(a3 * inv + sk.w, 0.f);
  int rt = n >> 6, rf = (n >> 4) & 3, ir = n & 15;
  int kg = (lane & 7) >> 1, jj = 4 * (lane & 1);
  ushort4 w4;
  w4.x = f2bf(o0); w4.y = f2bf(o1); w4.z = f2bf(o2); w4.w = f2bf(o3);
  *(ushort4*)&ha[(size_t)rt * 16384 + h * 2048 + rf * 512 + (ir + 16 * kg) * 8 + jj] = w4;
}

// ---------------- attention layer 2 (1 head x 32) ----------------
__global__ __launch_bounds__(64)
void attn2_kernel(const float* __restrict__ qkvs2, const unsigned short* __restrict__ e2b,
                  const int* __restrict__ srcs, const int* __restrict__ rowptr,
                  float* __restrict__ outp) {
  const int n = blockIdx.x;
  const int tid = threadIdx.x;
  const int c = tid & 31;
  const int beg = rowptr[n], end = rowptr[n + 1];
  const float qv = qkvs2[(size_t)n * 128 + c];
  float m = -INFINITY, den = 0.f, acc = 0.f;
  for (int i = beg; i < end; ++i) {
    const int s = srcs[i];
    const float ev = bf2f(e2b[(size_t)i * 32 + c]);
    const float kv = qkvs2[(size_t)s * 128 + 32 + c] + ev;
    const float vv = qkvs2[(size_t)s * 128 + 64 + c] + ev;
    float p = qv * kv;
#pragma unroll
    for (int off = 16; off; off >>= 1) p += __shfl_xor(p, off);
    p *= 0.17677669529663687f;
    const float mn = fmaxf(m, p);
    const float sc = __expf(m - mn);
    const float w = __expf(p - mn);
    den = den * sc + w;
    acc = acc * sc + w * vv;
    m = mn;
  }
  if (tid < 32) {
    float o = acc / (den + 1e-16f) + qkvs2[(size_t)n * 128 + 96 + c];
    outp[(size_t)n * CH + c] = fmaxf(o, 0.f);
  }
}

// ---------------- launcher ----------------
extern "C" void kernel_launch(void* const* d_in, const int* in_sizes, int n_in,
                              void* d_out, int out_size, void* d_ws, size_t ws_size,
                              hipStream_t stream) {
  const float* x   = (const float*)d_in[0];
  const float* lu  = (const float*)d_in[1];
  const int*   ei  = (const int*)d_in[2];
  const float* tt  = (const float*)d_in[3];
  const float* msg = (const float*)d_in[4];
  const float* tw  = (const float*)d_in[5];
  const float* tb  = (const float*)d_in[6];
  const float* Wq1 = (const float*)d_in[7];  const float* bq1 = (const float*)d_in[8];
  const float* Wk1 = (const float*)d_in[9];  const float* bk1 = (const float*)d_in[10];
  const float* Wv1 = (const float*)d_in[11]; const float* bv1 = (const float*)d_in[12];
  const float* We1 = (const float*)d_in[13];
  const float* Ws1 = (const float*)d_in[14]; const float* bs1 = (const float*)d_in[15];
  const float* Wq2 = (const float*)d_in[16]; const float* bq2 = (const float*)d_in[17];
  const float* Wk2 = (const float*)d_in[18]; const float* bk2 = (const float*)d_in[19];
  const float* Wv2 = (const float*)d_in[20]; const float* bv2 = (const float*)d_in[21];
  const float* We2 = (const float*)d_in[22];
  const float* Ws2 = (const float*)d_in[23]; const float* bs2 = (const float*)d_in[24];

  const int* srcp = ei;
  const int* dstp = ei + N_EDGES;

  char* p = (char*)d_ws;
  auto alloc = [&](size_t bytes) -> char* {
    char* r = p;
    p += (bytes + 255) & ~(size_t)255;
    return r;
  };
  int*   deg    = (int*)alloc((size_t)N_NODES * 4);
  int*   fill   = (int*)alloc((size_t)N_NODES * 4);
  int*   rowptr = (int*)alloc((size_t)(N_NODES + 1) * 4);
  int*   eid    = (int*)alloc((size_t)N_EDGES * 4);
  int*   srcs   = (int*)alloc((size_t)N_EDGES * 4);
  float* rel_s  = (float*)alloc((size_t)N_EDGES * 4);
  unsigned short* msgf = (unsigned short*)alloc((size_t)RTE * 16384);     // 39 MB (8192 ush/rt)
  unsigned short* xa   = (unsigned short*)alloc((size_t)RT1 * 32768);
  unsigned short* W1f  = (unsigned short*)alloc((size_t)8 * 64 * 1024);
  unsigned short* We1f = (unsigned short*)alloc((size_t)8 * 16 * 1024);
  unsigned short* W2f  = (unsigned short*)alloc((size_t)8 * 8 * 1024);
  unsigned short* We2f = (unsigned short*)alloc((size_t)8 * 4 * 1024);
  float* bcat1  = (float*)alloc(1024 * 4);
  float* bcat2  = (float*)alloc(128 * 4);
  float* qf     = (float*)alloc((size_t)N_NODES * 256 * 4);
  unsigned short* kvb = (unsigned short*)alloc((size_t)N_NODES * 512 * 2);
  float* sf     = (float*)alloc((size_t)N_NODES * 256 * 4);
  unsigned short* e1b = (unsigned short*)alloc((size_t)N_EDGES * 256 * 2);   // 82 MB
  unsigned short* ha  = (unsigned short*)alloc((size_t)RT1 * 32768);
  float* qkvs2  = (float*)alloc((size_t)N_NODES * 128 * 4);
  unsigned short* e2b = (unsigned short*)alloc((size_t)N_EDGES * 32 * 2);
  float* outp   = (float*)d_out;

  hipMemsetAsync(deg, 0, (size_t)N_NODES * 4, stream);
  hipMemsetAsync(fill, 0, (size_t)N_NODES * 4, stream);
  hipMemsetAsync(We2f, 0, (size_t)8 * 4 * 1024 * 2, stream);
  hipMemsetAsync(ha + (size_t)(RT1 - 1) * 16384, 0, 32768, stream);  // zero pad rows 10000-10047

  count_kernel<<<625, 256, 0, stream>>>(dstp, deg, N_EDGES);
  scan_kernel<<<1, 1024, 0, stream>>>(deg, rowptr, N_NODES);
  scatter_kernel<<<625, 256, 0, stream>>>(dstp, rowptr, fill, eid, N_EDGES);
  relsort_kernel<<<625, 256, 0, stream>>>(lu, srcp, tt, eid, rel_s, srcs, N_EDGES);
  msg_gather_kernel<<<N_EDGES * 16 / 256, 256, 0, stream>>>(msg, eid, msgf);

  conv_x_kernel<<<ceildiv(RT1 * 64 * 32, 256), 256, 0, stream>>>(x, xa, N_NODES, RT1);
  conv_all_kernel<<<ceildiv(369792, 256), 256, 0, stream>>>(
      Wq1, Wk1, Wv1, Ws1, We1, Wq2, Wk2, Wv2, Ws2, We2,
      bq1, bk1, bv1, bs1, bq2, bk2, bv2, bs2,
      W1f, We1f, W2f, We2f, bcat1, bcat2);

  // node1: quad-routed epilogue (q f32 | k bf16 | v bf16 | s f32)
  gemm_mfma<1, 2, false><<<dim3(RT1, 4), 256, 0, stream>>>(
      xa, W1f, bcat1, qf, kvb, sf, RT1, N_NODES, 64, 256, 0, 0,
      nullptr, nullptr, nullptr, nullptr);
  // e1: synthesized A (cos + msgf linear), bf16 out
  gemm_mfma<1, 1, true><<<dim3(RTE, 1), 256, 0, stream>>>(
      nullptr, We1f, nullptr, e1b, nullptr, nullptr, RTE, N_EDGES, 16, 256, 256, 0,
      rel_s, tw, tb, msgf);
  attn1_kernel<<<N_NODES, 64, 0, stream>>>(qf, kvb, sf, e1b, srcs, rowptr, ha);

  // node2: f32 out [n][128]
  gemm_mfma<2, 0, false><<<dim3(ceildiv(RT1, 2), 1), 256, 0, stream>>>(
      ha, W2f, bcat2, qkvs2, nullptr, nullptr, RT1, N_NODES, 8, 128, 128, 0,
      nullptr, nullptr, nullptr, nullptr);
  // e2: synthesized A, bf16 out [i][32]
  gemm_mfma<4, 1, true><<<dim3(RTE / 4, 1), 256, 0, stream>>>(
      nullptr, We2f, nullptr, e2b, nullptr, nullptr, RTE, N_EDGES, 4, 32, 32, 0,
      rel_s, tw, tb, msgf);
  attn2_kernel<<<N_NODES, 64, 0, stream>>>(qkvs2, e2b, srcs, rowptr, outp);
}

// Round 6
// 222.063 us; speedup vs baseline: 1.1509x; 1.1509x over previous
//
#include <hip/hip_runtime.h>
#include <math.h>

#define N_NODES 10000
#define N_EDGES 160000
#define D 256
#define H1 8
#define CH 32
#define TDIM 128
#define MSGD 128
#define RT1 157      // ceil(10000/64)
#define RTE 2500     // 160000/64

static inline int ceildiv(int a, int b) { return (a + b - 1) / b; }

typedef float f32x4 __attribute__((ext_vector_type(4)));
typedef short bf16x8 __attribute__((ext_vector_type(8)));

__device__ __forceinline__ unsigned short f2bf(float f) {
  unsigned int u = __builtin_bit_cast(unsigned int, f);
  u += 0x7FFFu + ((u >> 16) & 1u);   // RNE
  return (unsigned short)(u >> 16);
}
__device__ __forceinline__ float bf2f(unsigned short h) {
  unsigned int u = ((unsigned int)h) << 16;
  return __builtin_bit_cast(float, u);
}

// ---------------- prep ----------------
__global__ void rel_kernel(const float* __restrict__ lu, const int* __restrict__ srcp,
                           const float* __restrict__ tt, float* __restrict__ rel, int E) {
  for (int i = blockIdx.x * blockDim.x + threadIdx.x; i < E; i += gridDim.x * blockDim.x)
    rel[i] = lu[srcp[i]] - tt[i];
}

__global__ void count_kernel(const int* __restrict__ dstp, int* __restrict__ deg, int E) {
  for (int i = blockIdx.x * blockDim.x + threadIdx.x; i < E; i += gridDim.x * blockDim.x)
    atomicAdd(&deg[dstp[i]], 1);
}

// 1024 threads x 10 elements each; ~20 barriers total
__global__ void scan_kernel(const int* __restrict__ deg, int* __restrict__ rowptr, int n) {
  __shared__ int part[1024];
  const int tid = threadIdx.x;
  const int CHK = 10;
  int base = tid * CHK;
  int loc[CHK];
  int s = 0;
#pragma unroll
  for (int j = 0; j < CHK; ++j) {
    int idx = base + j;
    int v = (idx < n) ? deg[idx] : 0;
    loc[j] = s; s += v;
  }
  part[tid] = s;
  __syncthreads();
  for (int off = 1; off < 1024; off <<= 1) {
    int y = (tid >= off) ? part[tid - off] : 0;
    __syncthreads();
    part[tid] += y;
    __syncthreads();
  }
  int pre = tid ? part[tid - 1] : 0;
#pragma unroll
  for (int j = 0; j < CHK; ++j) {
    int idx = base + j;
    if (idx < n) rowptr[idx] = pre + loc[j];
  }
  if (tid == 1023) rowptr[n] = part[1023];
}

// emits sortpos (edge -> sorted slot) and srcs (sorted src list); no eid needed
__global__ void scatter_kernel(const int* __restrict__ srcp, const int* __restrict__ dstp,
                               const int* __restrict__ rowptr, int* __restrict__ fill,
                               int* __restrict__ sortpos, int* __restrict__ srcs, int E) {
  for (int e = blockIdx.x * blockDim.x + threadIdx.x; e < E; e += gridDim.x * blockDim.x) {
    int d = dstp[e];
    int pos = atomicAdd(&fill[d], 1);
    int slot = rowptr[d] + pos;
    sortpos[e] = slot;
    srcs[slot] = srcp[e];
  }
}

// ---------------- operand-layout converters ----------------
// A frag layout (ushorts): addr(i,k) = rt*16384 + ks*2048 + rf*512 + (ir+16*kg)*8 + j
//   rt=i>>6, rf=(i>>4)&3, ir=i&15 ; ks=k>>5, kg=(k>>3)&3, j=k&7
// B frag layout: addr(k,c) = (ks*NFtot + (c>>4))*512 + ((c&15)+16*kg)*8 + j

__global__ void conv_x_kernel(const float* __restrict__ x, unsigned short* __restrict__ xa,
                              int M, int RT) {
  int t = blockIdx.x * blockDim.x + threadIdx.x;
  if (t >= RT * 64 * 32) return;
  int i = t >> 5, k8 = t & 31;
  int k = k8 * 8;
  union { uint4 q; unsigned short s[8]; } u;
  if (i < M) {
    const float4* px = (const float4*)(x + (size_t)i * 256 + k);
    float4 f0 = px[0], f1 = px[1];
    u.s[0]=f2bf(f0.x); u.s[1]=f2bf(f0.y); u.s[2]=f2bf(f0.z); u.s[3]=f2bf(f0.w);
    u.s[4]=f2bf(f1.x); u.s[5]=f2bf(f1.y); u.s[6]=f2bf(f1.z); u.s[7]=f2bf(f1.w);
  } else {
    u.q = make_uint4(0,0,0,0);
  }
  int rt=i>>6, rf=(i>>4)&3, ir=i&15, ks=k8>>2, kg=k8&3;
  *(uint4*)&xa[(size_t)rt*16384 + ks*2048 + rf*512 + (ir+16*kg)*8] = u.q;
}

__device__ __forceinline__ void wstore(const float* __restrict__ W, unsigned short* __restrict__ out,
                                       int Nin, int n_off, int NFtot, int k, int c) {
  int gc = n_off + c;
  int ks=k>>5, kg=(k>>3)&3, j=k&7, nf=gc>>4, ic=gc&15;
  out[(size_t)(ks*NFtot+nf)*512 + (ic+16*kg)*8 + j] = f2bf(W[(size_t)k*Nin + c]);
}

__global__ void conv_all_kernel(const float* Wq1, const float* Wk1, const float* Wv1, const float* Ws1,
                                const float* We1, const float* Wq2, const float* Wk2, const float* Wv2,
                                const float* Ws2, const float* We2,
                                const float* bq1, const float* bk1, const float* bv1, const float* bs1,
                                const float* bq2, const float* bk2, const float* bv2, const float* bs2,
                                unsigned short* W1f, unsigned short* We1f, unsigned short* W2f,
                                unsigned short* We2f, float* bcat1, float* bcat2) {
  int t = blockIdx.x * blockDim.x + threadIdx.x;
  if (t < 262144) {               // W1f: 4 x 256x256
    int w = t >> 16, r = t & 65535, k = r >> 8, c = r & 255;
    const float* W = (w == 0) ? Wq1 : (w == 1) ? Wk1 : (w == 2) ? Wv1 : Ws1;
    wstore(W, W1f, 256, w * 256, 64, k, c);
  } else if (t < 327680) {        // We1f: 256x256
    int r = t - 262144, k = r >> 8, c = r & 255;
    wstore(We1, We1f, 256, 0, 16, k, c);
  } else if (t < 360448) {        // W2f: 4 x 256x32
    int r = t - 327680, w = r >> 13, r2 = r & 8191, k = r2 >> 5, c = r2 & 31;
    const float* W = (w == 0) ? Wq2 : (w == 1) ? Wk2 : (w == 2) ? Wv2 : Ws2;
    wstore(W, W2f, 32, w * 32, 8, k, c);
  } else if (t < 368640) {        // We2f: 256x32, NFtot=4 (only frags 0,1 ever read)
    int r = t - 360448, k = r >> 5, c = r & 31;
    wstore(We2, We2f, 32, 0, 4, k, c);
  } else if (t < 369792) {        // biases
    int r = t - 368640;
    if (r < 1024) {
      const float* b = (r < 256) ? bq1 : (r < 512) ? bk1 : (r < 768) ? bv1 : bs1;
      bcat1[r] = b[r & 255];
    } else {
      int r2 = r - 1024;
      const float* b = (r2 < 32) ? bq2 : (r2 < 64) ? bk2 : (r2 < 96) ? bv2 : bs2;
      bcat2[r2] = b[r2 & 31];
    }
  }
}

// ---------------- MFMA GEMM ----------------
// Wave tile 64x64 (4x4 frags), 4 waves/block. K=256 (8 K-steps of 32), K-order
// staggered per block (ks = ksi ^ (bx&7)). 2-deep ping-pong prefetch on the A
// stream (HBM); 1-deep on B (L2-resident weights).
// EPI 0: f32 direct stores (node2).
// EPI 1: e1+e2 fused edge GEMM. A synthesized in ORIGINAL edge order
//        (cos(rel*tw+tb) | linear f32 msg read); waves 0,1 carry 2 extra e2
//        col-frags (B2 = We2f). Epilogue scatter-writes rows to sorted slots
//        via sortpos (512B/64B contiguous rows -> full-line HBM writes).
// EPI 2: node1 quad-route by blockIdx.y: y0->qf f32, y1/y2->kvb bf16, y3->sf f32.
template <int WRW, int EPI>
__global__ __launch_bounds__(256)
void gemm_mfma(const unsigned short* __restrict__ A, const unsigned short* __restrict__ B,
               const unsigned short* __restrict__ B2, const float* __restrict__ bias,
               void* __restrict__ C0, void* __restrict__ C1, void* __restrict__ C2,
               int RT, int M, int NFtot, int Creal, int Cstride,
               const float* __restrict__ rel, const float* __restrict__ tw,
               const float* __restrict__ tb, const float* __restrict__ msg,
               const int* __restrict__ sortpos) {
  constexpr int WCW = 4 / WRW;
  constexpr int ACH = WRW * 256;          // A 16B-chunks per K-step
  constexpr int BCH = WCW * 256;          // B chunks per K-step
  constexpr int B2CH = (EPI == 1) ? 128 : 0;
  constexpr int NCH = ACH + BCH + B2CH;
  constexpr int PA = ACH / 256;
  constexpr int PB = BCH / 256;
  constexpr int STAGE_B = NCH * 16;
  constexpr int EPIL_B = (EPI == 1) ? (9216 + 5120 + 256) : ((EPI == 2) ? 64 * 72 * 2 : 0);
  constexpr int LDS_B = (STAGE_B > EPIL_B) ? STAGE_B : EPIL_B;
  __shared__ char ldsraw[LDS_B];
  uint4* lds = (uint4*)ldsraw;

  const int tid = threadIdx.x;
  const int wid = tid >> 6, lane = tid & 63;
  const int wr = (WRW == 1) ? 0 : (wid >> 1);
  const int wc = (WRW == 1) ? wid : (wid & 1);
  const int rt0 = blockIdx.x * WRW;
  const int n0f = blockIdx.y * (WCW * 4);
  const int phase = blockIdx.x & 7;

  auto fetchA = [&](int ks, int c) -> uint4 {
    int rt = rt0 + (c >> 8);
    if (rt >= RT) rt = RT - 1;
    if constexpr (EPI == 1) {
      int rem = c & 255;
      int rf = rem >> 6, r2 = rem & 63, ir = r2 & 15, kg = r2 >> 4;
      int i = rt * 64 + rf * 16 + ir;       // original edge index
      int k8 = ks * 4 + kg;
      union { uint4 q; unsigned short s[8]; } u;
      if (k8 < 16) {
        float r = rel[i];
        const float4* twp = (const float4*)(tw + k8 * 8);
        const float4* tbp = (const float4*)(tb + k8 * 8);
        float4 w0 = twp[0], w1 = twp[1], b0 = tbp[0], b1 = tbp[1];
        u.s[0]=f2bf(__cosf(r*w0.x+b0.x)); u.s[1]=f2bf(__cosf(r*w0.y+b0.y));
        u.s[2]=f2bf(__cosf(r*w0.z+b0.z)); u.s[3]=f2bf(__cosf(r*w0.w+b0.w));
        u.s[4]=f2bf(__cosf(r*w1.x+b1.x)); u.s[5]=f2bf(__cosf(r*w1.y+b1.y));
        u.s[6]=f2bf(__cosf(r*w1.z+b1.z)); u.s[7]=f2bf(__cosf(r*w1.w+b1.w));
      } else {
        const float4* pm = (const float4*)(msg + (size_t)i * MSGD + (k8 - 16) * 8);
        float4 f0 = pm[0], f1 = pm[1];
        u.s[0]=f2bf(f0.x); u.s[1]=f2bf(f0.y); u.s[2]=f2bf(f0.z); u.s[3]=f2bf(f0.w);
        u.s[4]=f2bf(f1.x); u.s[5]=f2bf(f1.y); u.s[6]=f2bf(f1.z); u.s[7]=f2bf(f1.w);
      }
      return u.q;
    } else {
      return *(const uint4*)(A + (size_t)rt * 16384 + (size_t)ks * 2048 + (size_t)(c & 255) * 8);
    }
  };
  auto fetchB = [&](int ks, int cb) -> uint4 {
    return *(const uint4*)(B + ((size_t)ks * NFtot + n0f) * 512 + (size_t)cb * 8);
  };
  auto fetchB2 = [&](int ks, int cb) -> uint4 {
    return *(const uint4*)(B2 + ((size_t)ks * 4 + (cb >> 6)) * 512 + (size_t)(cb & 63) * 8);
  };

  uint4 stA0[PA], stA1[PA], stB[PB];
  uint4 stB2 = make_uint4(0, 0, 0, 0);
#pragma unroll
  for (int p = 0; p < PA; ++p) stA0[p] = fetchA(0 ^ phase, tid + p * 256);
#pragma unroll
  for (int p = 0; p < PA; ++p) stA1[p] = fetchA(1 ^ phase, tid + p * 256);
#pragma unroll
  for (int p = 0; p < PB; ++p) stB[p] = fetchB(0 ^ phase, tid + p * 256);
  if constexpr (EPI == 1) { if (tid < 128) stB2 = fetchB2(0 ^ phase, tid); }

  f32x4 acc[4][4];
  f32x4 acc2[4];
#pragma unroll
  for (int i = 0; i < 4; ++i) {
    acc2[i] = (f32x4){0.f, 0.f, 0.f, 0.f};
#pragma unroll
    for (int j = 0; j < 4; ++j) acc[i][j] = (f32x4){0.f, 0.f, 0.f, 0.f};
  }

#pragma unroll
  for (int ksi = 0; ksi < 8; ++ksi) {
    __syncthreads();
    if ((ksi & 1) == 0) {
#pragma unroll
      for (int p = 0; p < PA; ++p) lds[tid + p * 256] = stA0[p];
    } else {
#pragma unroll
      for (int p = 0; p < PA; ++p) lds[tid + p * 256] = stA1[p];
    }
#pragma unroll
    for (int p = 0; p < PB; ++p) lds[ACH + tid + p * 256] = stB[p];
    if constexpr (EPI == 1) { if (tid < 128) lds[ACH + BCH + tid] = stB2; }
    if (ksi < 6) {
      if ((ksi & 1) == 0) {
#pragma unroll
        for (int p = 0; p < PA; ++p) stA0[p] = fetchA((ksi + 2) ^ phase, tid + p * 256);
      } else {
#pragma unroll
        for (int p = 0; p < PA; ++p) stA1[p] = fetchA((ksi + 2) ^ phase, tid + p * 256);
      }
    }
    if (ksi < 7) {
#pragma unroll
      for (int p = 0; p < PB; ++p) stB[p] = fetchB((ksi + 1) ^ phase, tid + p * 256);
      if constexpr (EPI == 1) { if (tid < 128) stB2 = fetchB2((ksi + 1) ^ phase, tid); }
    }
    __syncthreads();
    bf16x8 a[4], b[4];
#pragma unroll
    for (int rf = 0; rf < 4; ++rf) a[rf] = *(const bf16x8*)&lds[(wr * 4 + rf) * 64 + lane];
#pragma unroll
    for (int cf = 0; cf < 4; ++cf) b[cf] = *(const bf16x8*)&lds[ACH + (wc * 4 + cf) * 64 + lane];
#pragma unroll
    for (int rf = 0; rf < 4; ++rf)
#pragma unroll
      for (int cf = 0; cf < 4; ++cf)
        acc[rf][cf] = __builtin_amdgcn_mfma_f32_16x16x32_bf16(a[rf], b[cf], acc[rf][cf], 0, 0, 0);
    if constexpr (EPI == 1) {
      if (wid < 2) {
        bf16x8 b2 = *(const bf16x8*)&lds[ACH + BCH + wid * 64 + lane];
#pragma unroll
        for (int rf = 0; rf < 4; ++rf)
          acc2[rf] = __builtin_amdgcn_mfma_f32_16x16x32_bf16(a[rf], b2, acc2[rf], 0, 0, 0);
      }
    }
  }

  // ---- epilogue ----  C/D frag: col=lane&15, row=(lane>>4)*4+reg
  if constexpr (EPI == 0) {
    float* dst = (float*)C0;
    const int row0 = (rt0 + wr) * 64 + ((lane >> 4) * 4);
    const int cb2 = blockIdx.y * (WCW * 64) + wc * 64 + (lane & 15);
#pragma unroll
    for (int cf = 0; cf < 4; ++cf) {
      int c = cb2 + cf * 16;
      if (c >= Creal) continue;
      float bv = bias ? bias[c] : 0.f;
#pragma unroll
      for (int rf = 0; rf < 4; ++rf) {
#pragma unroll
        for (int j = 0; j < 4; ++j) {
          int r = row0 + rf * 16 + j;
          if (r < M) dst[(size_t)r * Cstride + c] = acc[rf][cf][j] + bv;
        }
      }
    }
  } else if constexpr (EPI == 1) {
    // scatter-write e1 (64x256) and e2 (64x32) rows to sorted slots
    __syncthreads();
    unsigned short* cl  = (unsigned short*)ldsraw;            // [64][72]
    unsigned short* cl2 = (unsigned short*)(ldsraw + 9216);   // [64][40]
    int* spos = (int*)(ldsraw + 14336);                       // [64]
    if (tid < 64) spos[tid] = sortpos[rt0 * 64 + tid];
    const int fr0 = (lane >> 4) * 4;
    const int fc0 = lane & 15;
    if (wid < 2) {
#pragma unroll
      for (int rf = 0; rf < 4; ++rf)
#pragma unroll
        for (int j = 0; j < 4; ++j)
          cl2[(fr0 + rf * 16 + j) * 40 + wid * 16 + fc0] = f2bf(acc2[rf][j]);
    }
    unsigned short* e1o = (unsigned short*)C0;
    unsigned short* e2o = (unsigned short*)C1;
    for (int pass = 0; pass < 4; ++pass) {
      if (wid == pass) {
#pragma unroll
        for (int cf = 0; cf < 4; ++cf) {
          int c = fc0 + cf * 16;
#pragma unroll
          for (int rf = 0; rf < 4; ++rf)
#pragma unroll
            for (int j = 0; j < 4; ++j)
              cl[(fr0 + rf * 16 + j) * 72 + c] = f2bf(acc[rf][cf][j]);
        }
      }
      __syncthreads();
#pragma unroll
      for (int id = tid; id < 512; id += 256) {
        int row = id >> 3, cc = (id & 7) * 8;
        int gr = spos[row];
        *(uint4*)&e1o[(size_t)gr * 256 + pass * 64 + cc] = *(const uint4*)&cl[row * 72 + cc];
      }
      __syncthreads();
    }
    {
      int row = tid >> 2, cc = (tid & 3) * 8;
      int gr = spos[row];
      *(uint4*)&e2o[(size_t)gr * 32 + cc] = *(const uint4*)&cl2[row * 40 + cc];
    }
  } else {
    // EPI == 2: node1 quad-route
    const int y = blockIdx.y;
    bool bf16path;
    void* dstp_; int cstr_, dc0_, bcol0_;
    if (y == 0)      { bf16path = false; dstp_ = C0; cstr_ = 256; dc0_ = 0;   bcol0_ = 0; }
    else if (y == 1) { bf16path = true;  dstp_ = C1; cstr_ = 512; dc0_ = 0;   bcol0_ = 256; }
    else if (y == 2) { bf16path = true;  dstp_ = C1; cstr_ = 512; dc0_ = 256; bcol0_ = 512; }
    else             { bf16path = false; dstp_ = C2; cstr_ = 256; dc0_ = 0;   bcol0_ = 768; }
    if (!bf16path) {
      float* dst = (float*)dstp_;
      const int row0 = (rt0 + wr) * 64 + ((lane >> 4) * 4);
      const int cb2 = wc * 64 + (lane & 15);
#pragma unroll
      for (int cf = 0; cf < 4; ++cf) {
        int c = cb2 + cf * 16;
        float bv = bias[bcol0_ + c];
#pragma unroll
        for (int rf = 0; rf < 4; ++rf) {
#pragma unroll
          for (int j = 0; j < 4; ++j) {
            int r = row0 + rf * 16 + j;
            if (r < M) dst[(size_t)r * cstr_ + c] = acc[rf][cf][j] + bv;
          }
        }
      }
    } else {
      __syncthreads();
      unsigned short* cl = (unsigned short*)ldsraw;   // [64][72]
      unsigned short* dst = (unsigned short*)dstp_;
      const int fr0 = (lane >> 4) * 4;
      const int fc0 = lane & 15;
      for (int pass = 0; pass < 4; ++pass) {
        if (wid == pass) {
#pragma unroll
          for (int cf = 0; cf < 4; ++cf) {
            int c = fc0 + cf * 16;
            float bv = bias[bcol0_ + pass * 64 + c];
#pragma unroll
            for (int rf = 0; rf < 4; ++rf)
#pragma unroll
              for (int j = 0; j < 4; ++j)
                cl[(fr0 + rf * 16 + j) * 72 + c] = f2bf(acc[rf][cf][j] + bv);
          }
        }
        __syncthreads();
#pragma unroll
        for (int id = tid; id < 512; id += 256) {
          int row = id >> 3, cc = (id & 7) * 8;
          int gr = rt0 * 64 + row;
          if (gr < M)
            *(uint4*)&dst[(size_t)gr * cstr_ + dc0_ + pass * 64 + cc] = *(const uint4*)&cl[row * 72 + cc];
        }
        __syncthreads();
      }
    }
  }
}

// ---------------- attention layer 1 (8 heads x 32, concat) ----------------
// 1 wave per dst node; lane -> (head lane>>3, 4 channels (lane&7)*4). Online softmax.
__global__ __launch_bounds__(64)
void attn1_kernel(const float* __restrict__ qf, const unsigned short* __restrict__ kvb,
                  const float* __restrict__ sf, const unsigned short* __restrict__ e1b,
                  const int* __restrict__ srcs, const int* __restrict__ rowptr,
                  unsigned short* __restrict__ ha) {
  const int n = blockIdx.x;
  const int lane = threadIdx.x;
  const int h = lane >> 3;
  const int c0 = (lane & 7) * 4;
  const int off = h * 32 + c0;
  const int beg = rowptr[n], end = rowptr[n + 1];
  const float4 q = *(const float4*)&qf[(size_t)n * 256 + off];
  float m = -INFINITY, den = 0.f;
  float a0 = 0.f, a1 = 0.f, a2 = 0.f, a3 = 0.f;
  for (int i = beg; i < end; ++i) {
    const int s = srcs[i];
    ushort4 ev = *(const ushort4*)&e1b[(size_t)i * 256 + off];
    ushort4 kk = *(const ushort4*)&kvb[(size_t)s * 512 + off];
    ushort4 vv = *(const ushort4*)&kvb[(size_t)s * 512 + 256 + off];
    float e0 = bf2f(ev.x), e1 = bf2f(ev.y), e2 = bf2f(ev.z), e3 = bf2f(ev.w);
    float k0 = bf2f(kk.x) + e0, k1 = bf2f(kk.y) + e1, k2 = bf2f(kk.z) + e2, k3 = bf2f(kk.w) + e3;
    float v0 = bf2f(vv.x) + e0, v1 = bf2f(vv.y) + e1, v2 = bf2f(vv.z) + e2, v3 = bf2f(vv.w) + e3;
    float p = q.x * k0 + q.y * k1 + q.z * k2 + q.w * k3;
    p += __shfl_xor(p, 1); p += __shfl_xor(p, 2); p += __shfl_xor(p, 4);
    p *= 0.17677669529663687f;   // 1/sqrt(32)
    const float mn = fmaxf(m, p);
    const float sc = __expf(m - mn);
    const float w = __expf(p - mn);
    den = den * sc + w;
    a0 = a0 * sc + w * v0; a1 = a1 * sc + w * v1;
    a2 = a2 * sc + w * v2; a3 = a3 * sc + w * v3;
    m = mn;
  }
  const float inv = 1.f / (den + 1e-16f);
  const float4 sk = *(const float4*)&sf[(size_t)n * 256 + off];
  float o0 = fmaxf(a0 * inv + sk.x, 0.f);
  float o1 = fmaxf(a1 * inv + sk.y, 0.f);
  float o2 = fmaxf(a2 * inv + sk.z, 0.f);
  float o3 = fmaxf(a3 * inv + sk.w, 0.f);
  int rt = n >> 6, rf = (n >> 4) & 3, ir = n & 15;
  int kg = (lane & 7) >> 1, jj = 4 * (lane & 1);
  ushort4 w4;
  w4.x = f2bf(o0); w4.y = f2bf(o1); w4.z = f2bf(o2); w4.w = f2bf(o3);
  *(ushort4*)&ha[(size_t)rt * 16384 + h * 2048 + rf * 512 + (ir + 16 * kg) * 8 + jj] = w4;
}

// ---------------- attention layer 2 (1 head x 32) ----------------
__global__ __launch_bounds__(64)
void attn2_kernel(const float* __restrict__ qkvs2, const unsigned short* __restrict__ e2b,
                  const int* __restrict__ srcs, const int* __restrict__ rowptr,
                  float* __restrict__ outp) {
  const int n = blockIdx.x;
  const int tid = threadIdx.x;
  const int c = tid & 31;
  const int beg = rowptr[n], end = rowptr[n + 1];
  const float qv = qkvs2[(size_t)n * 128 + c];
  float m = -INFINITY, den = 0.f, acc = 0.f;
  for (int i = beg; i < end; ++i) {
    const int s = srcs[i];
    const float ev = bf2f(e2b[(size_t)i * 32 + c]);
    const float kv = qkvs2[(size_t)s * 128 + 32 + c] + ev;
    const float vv = qkvs2[(size_t)s * 128 + 64 + c] + ev;
    float p = qv * kv;
#pragma unroll
    for (int off = 16; off; off >>= 1) p += __shfl_xor(p, off);
    p *= 0.17677669529663687f;
    const float mn = fmaxf(m, p);
    const float sc = __expf(m - mn);
    const float w = __expf(p - mn);
    den = den * sc + w;
    acc = acc * sc + w * vv;
    m = mn;
  }
  if (tid < 32) {
    float o = acc / (den + 1e-16f) + qkvs2[(size_t)n * 128 + 96 + c];
    outp[(size_t)n * CH + c] = fmaxf(o, 0.f);
  }
}

// ---------------- launcher ----------------
extern "C" void kernel_launch(void* const* d_in, const int* in_sizes, int n_in,
                              void* d_out, int out_size, void* d_ws, size_t ws_size,
                              hipStream_t stream) {
  const float* x   = (const float*)d_in[0];
  const float* lu  = (const float*)d_in[1];
  const int*   ei  = (const int*)d_in[2];
  const float* tt  = (const float*)d_in[3];
  const float* msg = (const float*)d_in[4];
  const float* tw  = (const float*)d_in[5];
  const float* tb  = (const float*)d_in[6];
  const float* Wq1 = (const float*)d_in[7];  const float* bq1 = (const float*)d_in[8];
  const float* Wk1 = (const float*)d_in[9];  const float* bk1 = (const float*)d_in[10];
  const float* Wv1 = (const float*)d_in[11]; const float* bv1 = (const float*)d_in[12];
  const float* We1 = (const float*)d_in[13];
  const float* Ws1 = (const float*)d_in[14]; const float* bs1 = (const float*)d_in[15];
  const float* Wq2 = (const float*)d_in[16]; const float* bq2 = (const float*)d_in[17];
  const float* Wk2 = (const float*)d_in[18]; const float* bk2 = (const float*)d_in[19];
  const float* Wv2 = (const float*)d_in[20]; const float* bv2 = (const float*)d_in[21];
  const float* We2 = (const float*)d_in[22];
  const float* Ws2 = (const float*)d_in[23]; const float* bs2 = (const float*)d_in[24];

  const int* srcp = ei;
  const int* dstp = ei + N_EDGES;

  char* p = (char*)d_ws;
  auto alloc = [&](size_t bytes) -> char* {
    char* r = p;
    p += (bytes + 255) & ~(size_t)255;
    return r;
  };
  int*   deg     = (int*)alloc((size_t)N_NODES * 4);
  int*   fill    = (int*)alloc((size_t)N_NODES * 4);
  int*   rowptr  = (int*)alloc((size_t)(N_NODES + 1) * 4);
  int*   sortpos = (int*)alloc((size_t)N_EDGES * 4);
  int*   srcs    = (int*)alloc((size_t)N_EDGES * 4);
  float* rel     = (float*)alloc((size_t)N_EDGES * 4);
  unsigned short* xa   = (unsigned short*)alloc((size_t)RT1 * 32768);
  unsigned short* W1f  = (unsigned short*)alloc((size_t)8 * 64 * 1024);
  unsigned short* We1f = (unsigned short*)alloc((size_t)8 * 16 * 1024);
  unsigned short* W2f  = (unsigned short*)alloc((size_t)8 * 8 * 1024);
  unsigned short* We2f = (unsigned short*)alloc((size_t)8 * 4 * 1024);
  float* bcat1  = (float*)alloc(1024 * 4);
  float* bcat2  = (float*)alloc(128 * 4);
  float* qf     = (float*)alloc((size_t)N_NODES * 256 * 4);
  unsigned short* kvb = (unsigned short*)alloc((size_t)N_NODES * 512 * 2);
  float* sf     = (float*)alloc((size_t)N_NODES * 256 * 4);
  unsigned short* e1b = (unsigned short*)alloc((size_t)N_EDGES * 256 * 2);   // 82 MB
  unsigned short* ha  = (unsigned short*)alloc((size_t)RT1 * 32768);
  float* qkvs2  = (float*)alloc((size_t)N_NODES * 128 * 4);
  unsigned short* e2b = (unsigned short*)alloc((size_t)N_EDGES * 32 * 2);
  float* outp   = (float*)d_out;

  hipMemsetAsync(deg, 0, (size_t)N_NODES * 4, stream);
  hipMemsetAsync(fill, 0, (size_t)N_NODES * 4, stream);
  hipMemsetAsync(ha + (size_t)(RT1 - 1) * 16384, 0, 32768, stream);  // zero pad rows 10000-10047

  rel_kernel<<<625, 256, 0, stream>>>(lu, srcp, tt, rel, N_EDGES);
  count_kernel<<<625, 256, 0, stream>>>(dstp, deg, N_EDGES);
  scan_kernel<<<1, 1024, 0, stream>>>(deg, rowptr, N_NODES);
  scatter_kernel<<<625, 256, 0, stream>>>(srcp, dstp, rowptr, fill, sortpos, srcs, N_EDGES);

  conv_x_kernel<<<ceildiv(RT1 * 64 * 32, 256), 256, 0, stream>>>(x, xa, N_NODES, RT1);
  conv_all_kernel<<<ceildiv(369792, 256), 256, 0, stream>>>(
      Wq1, Wk1, Wv1, Ws1, We1, Wq2, Wk2, Wv2, Ws2, We2,
      bq1, bk1, bv1, bs1, bq2, bk2, bv2, bs2,
      W1f, We1f, W2f, We2f, bcat1, bcat2);

  // node1: quad-routed epilogue (q f32 | k bf16 | v bf16 | s f32)
  gemm_mfma<1, 2><<<dim3(RT1, 4), 256, 0, stream>>>(
      xa, W1f, nullptr, bcat1, qf, kvb, sf, RT1, N_NODES, 64, 256, 256,
      nullptr, nullptr, nullptr, nullptr, nullptr);
  // e1+e2 fused edge GEMM: synth A (original order), scatter-write sorted
  gemm_mfma<1, 1><<<dim3(RTE, 1), 256, 0, stream>>>(
      nullptr, We1f, We2f, nullptr, e1b, e2b, nullptr, RTE, N_EDGES, 16, 256, 256,
      rel, tw, tb, msg, sortpos);
  attn1_kernel<<<N_NODES, 64, 0, stream>>>(qf, kvb, sf, e1b, srcs, rowptr, ha);

  // node2: f32 out [n][128]
  gemm_mfma<2, 0><<<dim3(ceildiv(RT1, 2), 1), 256, 0, stream>>>(
      ha, W2f, nullptr, bcat2, qkvs2, nullptr, nullptr, RT1, N_NODES, 8, 128, 128,
      nullptr, nullptr, nullptr, nullptr, nullptr);
  attn2_kernel<<<N_NODES, 64, 0, stream>>>(qkvs2, e2b, srcs, rowptr, outp);
}

// Round 7
// 191.917 us; speedup vs baseline: 1.3317x; 1.1571x over previous
//
#include <hip/hip_runtime.h>
#include <math.h>

#define N_NODES 10000
#define N_EDGES 160000
#define RT1 157      // ceil(10000/64)
#define RTE 2500     // 160000/64
#define CONVX_T (RT1 * 64 * 32)   // 321536

static inline int ceildiv(int a, int b) { return (a + b - 1) / b; }

typedef float f32x4 __attribute__((ext_vector_type(4)));
typedef short bf16x8 __attribute__((ext_vector_type(8)));

__device__ __forceinline__ unsigned short f2bf(float f) {
  unsigned int u = __builtin_bit_cast(unsigned int, f);
  u += 0x7FFFu + ((u >> 16) & 1u);   // RNE
  return (unsigned short)(u >> 16);
}
__device__ __forceinline__ float bf2f(unsigned short h) {
  unsigned int u = ((unsigned int)h) << 16;
  return __builtin_bit_cast(float, u);
}

// ---------------- prep: rel + degree count fused ----------------
__global__ void prep1_kernel(const float* __restrict__ lu, const int* __restrict__ srcp,
                             const int* __restrict__ dstp, const float* __restrict__ tt,
                             float* __restrict__ rel, int* __restrict__ deg, int E) {
  for (int i = blockIdx.x * blockDim.x + threadIdx.x; i < E; i += gridDim.x * blockDim.x) {
    rel[i] = lu[srcp[i]] - tt[i];
    atomicAdd(&deg[dstp[i]], 1);
  }
}

// 1024 threads x 10 elements each
__global__ void scan_kernel(const int* __restrict__ deg, int* __restrict__ rowptr, int n) {
  __shared__ int part[1024];
  const int tid = threadIdx.x;
  const int CHK = 10;
  int base = tid * CHK;
  int loc[CHK];
  int s = 0;
#pragma unroll
  for (int j = 0; j < CHK; ++j) {
    int idx = base + j;
    int v = (idx < n) ? deg[idx] : 0;
    loc[j] = s; s += v;
  }
  part[tid] = s;
  __syncthreads();
  for (int off = 1; off < 1024; off <<= 1) {
    int y = (tid >= off) ? part[tid - off] : 0;
    __syncthreads();
    part[tid] += y;
    __syncthreads();
  }
  int pre = tid ? part[tid - 1] : 0;
#pragma unroll
  for (int j = 0; j < CHK; ++j) {
    int idx = base + j;
    if (idx < n) rowptr[idx] = pre + loc[j];
  }
  if (tid == 1023) rowptr[n] = part[1023];
}

__global__ void scatter_kernel(const int* __restrict__ srcp, const int* __restrict__ dstp,
                               const int* __restrict__ rowptr, int* __restrict__ fill,
                               int* __restrict__ sortpos, int* __restrict__ srcs, int E) {
  for (int e = blockIdx.x * blockDim.x + threadIdx.x; e < E; e += gridDim.x * blockDim.x) {
    int d = dstp[e];
    int pos = atomicAdd(&fill[d], 1);
    int slot = rowptr[d] + pos;
    sortpos[e] = slot;
    srcs[slot] = srcp[e];
  }
}

// ---------------- all format conversions in ONE launch ----------------
// A frag layout (ushorts): addr(i,k)= rt*16384 + ks*2048 + rf*512 + (ir+16*kg)*8 + j
// B frag layout: addr(k,c) = (ks*NFtot + (c>>4))*512 + ((c&15)+16*kg)*8 + j
__device__ __forceinline__ void wstore(const float* __restrict__ W, unsigned short* __restrict__ out,
                                       int Nin, int n_off, int NFtot, int k, int c) {
  int gc = n_off + c;
  int ks=k>>5, kg=(k>>3)&3, j=k&7, nf=gc>>4, ic=gc&15;
  out[(size_t)(ks*NFtot+nf)*512 + (ic+16*kg)*8 + j] = f2bf(W[(size_t)k*Nin + c]);
}

__global__ void conv_all_kernel(const float* __restrict__ x, unsigned short* __restrict__ xa,
                                const float* Wq1, const float* Wk1, const float* Wv1, const float* Ws1,
                                const float* We1, const float* Wq2, const float* Wk2, const float* Wv2,
                                const float* Ws2, const float* We2,
                                const float* bq1, const float* bk1, const float* bv1, const float* bs1,
                                const float* bq2, const float* bk2, const float* bv2, const float* bs2,
                                unsigned short* W1f, unsigned short* We1f, unsigned short* W2f,
                                unsigned short* We2f, float* bcat1, float* bcat2) {
  int t0 = blockIdx.x * blockDim.x + threadIdx.x;
  if (t0 < CONVX_T) {
    // x -> xa (A frag layout, zero-pad rows >= N_NODES)
    int i = t0 >> 5, k8 = t0 & 31;
    union { uint4 q; unsigned short s[8]; } u;
    if (i < N_NODES) {
      const float4* px = (const float4*)(x + (size_t)i * 256 + k8 * 8);
      float4 f0 = px[0], f1 = px[1];
      u.s[0]=f2bf(f0.x); u.s[1]=f2bf(f0.y); u.s[2]=f2bf(f0.z); u.s[3]=f2bf(f0.w);
      u.s[4]=f2bf(f1.x); u.s[5]=f2bf(f1.y); u.s[6]=f2bf(f1.z); u.s[7]=f2bf(f1.w);
    } else {
      u.q = make_uint4(0,0,0,0);
    }
    int rt=i>>6, rf=(i>>4)&3, ir=i&15, ks=k8>>2, kg=k8&3;
    *(uint4*)&xa[(size_t)rt*16384 + ks*2048 + rf*512 + (ir+16*kg)*8] = u.q;
    return;
  }
  int t = t0 - CONVX_T;
  if (t < 262144) {               // W1f: 4 x 256x256
    int w = t >> 16, r = t & 65535, k = r >> 8, c = r & 255;
    const float* W = (w == 0) ? Wq1 : (w == 1) ? Wk1 : (w == 2) ? Wv1 : Ws1;
    wstore(W, W1f, 256, w * 256, 64, k, c);
  } else if (t < 327680) {        // We1f: 256x256
    int r = t - 262144, k = r >> 8, c = r & 255;
    wstore(We1, We1f, 256, 0, 16, k, c);
  } else if (t < 360448) {        // W2f: 4 x 256x32
    int r = t - 327680, w = r >> 13, r2 = r & 8191, k = r2 >> 5, c = r2 & 31;
    const float* W = (w == 0) ? Wq2 : (w == 1) ? Wk2 : (w == 2) ? Wv2 : Ws2;
    wstore(W, W2f, 32, w * 32, 8, k, c);
  } else if (t < 368640) {        // We2f: 256x32 (cols 32-63 pre-zeroed by memset)
    int r = t - 360448, k = r >> 5, c = r & 31;
    wstore(We2, We2f, 32, 0, 4, k, c);
  } else if (t < 369792) {        // biases
    int r = t - 368640;
    if (r < 1024) {
      const float* b = (r < 256) ? bq1 : (r < 512) ? bk1 : (r < 768) ? bv1 : bs1;
      bcat1[r] = b[r & 255];
    } else {
      int r2 = r - 1024;
      const float* b = (r2 < 32) ? bq2 : (r2 < 64) ? bk2 : (r2 < 96) ? bv2 : bs2;
      bcat2[r2] = b[r2 & 31];
    }
  }
}

// ---------------- BIG merged GEMM: edge(e1+e2) blocks + node1 blocks ----------------
// bx < RTE: edge block. rows 64 edges, cols 256 (We1) + 32 (We2). K=256.
//   cos half (ks 0-3) precomputed ONCE into static LDS (no in-loop loads/VALU);
//   msg half (ks 4-7) reg-staged 2-deep; B reg-staged 2-deep; scatter epilogue.
// bx >= RTE: node1 block (rt = idx%RT1, y = idx/RT1 quad-route epilogue).
__global__ __launch_bounds__(256)
void big_gemm(const unsigned short* __restrict__ xa, const unsigned short* __restrict__ W1f,
              const float* __restrict__ bcat1, float* __restrict__ qf,
              unsigned short* __restrict__ kvb, float* __restrict__ sf,
              const unsigned short* __restrict__ We1f, const unsigned short* __restrict__ We2f,
              unsigned short* __restrict__ e1b, unsigned short* __restrict__ e2b,
              const float* __restrict__ rel, const float* __restrict__ tw,
              const float* __restrict__ tb, const float* __restrict__ msg,
              const int* __restrict__ sortpos) {
  __shared__ char ldsraw[38912];
  uint4* lds4 = (uint4*)ldsraw;
  const int tid = threadIdx.x;
  const int wid = tid >> 6, lane = tid & 63;
  const int bx = blockIdx.x;

  if (bx < RTE) {
    // ================= edge path =================
    const int rt0 = bx;
    const int phase = bx & 7;
    const int arf = tid >> 6, ar2 = tid & 63, air = ar2 & 15, akg = ar2 >> 4;
    const int aedge = rt0 * 64 + arf * 16 + air;   // original edge index for this thread's chunk

    // prologue: static cos region (ks 0..3), one chunk per thread per step
    {
      float rl = rel[aedge];
#pragma unroll
      for (int s = 0; s < 4; ++s) {
        int k8 = s * 4 + akg;
        const float4* twp = (const float4*)(tw + k8 * 8);
        const float4* tbp = (const float4*)(tb + k8 * 8);
        float4 w0 = twp[0], w1 = twp[1], b0 = tbp[0], b1 = tbp[1];
        union { uint4 q; unsigned short us[8]; } u;
        u.us[0]=f2bf(__cosf(rl*w0.x+b0.x)); u.us[1]=f2bf(__cosf(rl*w0.y+b0.y));
        u.us[2]=f2bf(__cosf(rl*w0.z+b0.z)); u.us[3]=f2bf(__cosf(rl*w0.w+b0.w));
        u.us[4]=f2bf(__cosf(rl*w1.x+b1.x)); u.us[5]=f2bf(__cosf(rl*w1.y+b1.y));
        u.us[6]=f2bf(__cosf(rl*w1.z+b1.z)); u.us[7]=f2bf(__cosf(rl*w1.w+b1.w));
        lds4[s * 256 + tid] = u.q;
      }
    }

    auto fetchMsg = [&](int ks) -> uint4 {
      const float4* pm = (const float4*)(msg + (size_t)aedge * 128 + (size_t)(ks * 4 + akg - 16) * 8);
      float4 f0 = pm[0], f1 = pm[1];
      union { uint4 q; unsigned short us[8]; } u;
      u.us[0]=f2bf(f0.x); u.us[1]=f2bf(f0.y); u.us[2]=f2bf(f0.z); u.us[3]=f2bf(f0.w);
      u.us[4]=f2bf(f1.x); u.us[5]=f2bf(f1.y); u.us[6]=f2bf(f1.z); u.us[7]=f2bf(f1.w);
      return u.q;
    };
    auto fetchB = [&](int ks, int p) -> uint4 {
      return *(const uint4*)(We1f + (size_t)ks * 8192 + (size_t)(tid + p * 256) * 8);
    };
    auto fetchB2 = [&](int ks) -> uint4 {   // valid for tid < 128
      return *(const uint4*)(We2f + (size_t)(ks * 4 + (tid >> 6)) * 512 + (size_t)(tid & 63) * 8);
    };

    uint4 rB[2][4];
    uint4 rA[2];
    uint4 rB2 = make_uint4(0, 0, 0, 0);
    {
      int ks0 = 0 ^ phase, ks1 = 1 ^ phase;
#pragma unroll
      for (int p = 0; p < 4; ++p) rB[0][p] = fetchB(ks0, p);
#pragma unroll
      for (int p = 0; p < 4; ++p) rB[1][p] = fetchB(ks1, p);
      if (ks0 >= 4) rA[0] = fetchMsg(ks0);
      if (ks1 >= 4) rA[1] = fetchMsg(ks1);
      if (tid < 128) rB2 = fetchB2(ks0);
    }

    f32x4 acc[4][4];
    f32x4 acc2[4];
#pragma unroll
    for (int i = 0; i < 4; ++i) {
      acc2[i] = (f32x4){0.f, 0.f, 0.f, 0.f};
#pragma unroll
      for (int j = 0; j < 4; ++j) acc[i][j] = (f32x4){0.f, 0.f, 0.f, 0.f};
    }

#pragma unroll
    for (int ksi = 0; ksi < 8; ++ksi) {
      const int ks = ksi ^ phase;
      const int sl = ksi & 1;
      __syncthreads();
#pragma unroll
      for (int p = 0; p < 4; ++p) lds4[1280 + tid + p * 256] = rB[sl][p];
      if (tid < 128) lds4[2304 + tid] = rB2;
      if (ks >= 4) lds4[1024 + tid] = rA[sl];
      if (ksi < 6) {
        int kf = (ksi + 2) ^ phase;
#pragma unroll
        for (int p = 0; p < 4; ++p) rB[sl][p] = fetchB(kf, p);
        if (kf >= 4) rA[sl] = fetchMsg(kf);
      }
      if (ksi < 7) {
        int kf1 = (ksi + 1) ^ phase;
        if (tid < 128) rB2 = fetchB2(kf1);
      }
      __syncthreads();
      bf16x8 a[4], b[4];
      const uint4* abase = (ks < 4) ? &lds4[ks * 256] : &lds4[1024];
#pragma unroll
      for (int rf = 0; rf < 4; ++rf) a[rf] = *(const bf16x8*)&abase[rf * 64 + lane];
#pragma unroll
      for (int cf = 0; cf < 4; ++cf) b[cf] = *(const bf16x8*)&lds4[1280 + (wid * 4 + cf) * 64 + lane];
#pragma unroll
      for (int rf = 0; rf < 4; ++rf)
#pragma unroll
        for (int cf = 0; cf < 4; ++cf)
          acc[rf][cf] = __builtin_amdgcn_mfma_f32_16x16x32_bf16(a[rf], b[cf], acc[rf][cf], 0, 0, 0);
      if (wid < 2) {
        bf16x8 b2 = *(const bf16x8*)&lds4[2304 + wid * 64 + lane];
#pragma unroll
        for (int rf = 0; rf < 4; ++rf)
          acc2[rf] = __builtin_amdgcn_mfma_f32_16x16x32_bf16(a[rf], b2, acc2[rf], 0, 0, 0);
      }
    }

    // epilogue: scatter e1 (64x256) and e2 (64x32) rows to sorted slots
    __syncthreads();
    unsigned short* cl  = (unsigned short*)ldsraw;            // [64][72]
    unsigned short* cl2 = (unsigned short*)(ldsraw + 9216);   // [64][40]
    int* spos = (int*)(ldsraw + 14336);                       // [64]
    if (tid < 64) spos[tid] = sortpos[rt0 * 64 + tid];
    const int fr0 = (lane >> 4) * 4;
    const int fc0 = lane & 15;
    if (wid < 2) {
#pragma unroll
      for (int rf = 0; rf < 4; ++rf)
#pragma unroll
        for (int j = 0; j < 4; ++j)
          cl2[(fr0 + rf * 16 + j) * 40 + wid * 16 + fc0] = f2bf(acc2[rf][j]);
    }
    for (int pass = 0; pass < 4; ++pass) {
      if (wid == pass) {
#pragma unroll
        for (int cf = 0; cf < 4; ++cf) {
          int c = fc0 + cf * 16;
#pragma unroll
          for (int rf = 0; rf < 4; ++rf)
#pragma unroll
            for (int j = 0; j < 4; ++j)
              cl[(fr0 + rf * 16 + j) * 72 + c] = f2bf(acc[rf][cf][j]);
        }
      }
      __syncthreads();
#pragma unroll
      for (int id = tid; id < 512; id += 256) {
        int row = id >> 3, cc = (id & 7) * 8;
        int gr = spos[row];
        *(uint4*)&e1b[(size_t)gr * 256 + pass * 64 + cc] = *(const uint4*)&cl[row * 72 + cc];
      }
      __syncthreads();
    }
    {
      int row = tid >> 2, cc = (tid & 3) * 8;
      int gr = spos[row];
      *(uint4*)&e2b[(size_t)gr * 32 + cc] = *(const uint4*)&cl2[row * 40 + cc];
    }
  } else {
    // ================= node1 path =================
    const int idx = bx - RTE;
    const int rt0 = idx % RT1;
    const int y = idx / RT1;
    const int phase = rt0 & 7;
    const int n0f = y * 16;

    auto fetchA = [&](int ks) -> uint4 {
      return *(const uint4*)(xa + (size_t)rt0 * 16384 + (size_t)ks * 2048 + (size_t)tid * 8);
    };
    auto fetchB = [&](int ks, int p) -> uint4 {
      return *(const uint4*)(W1f + ((size_t)ks * 64 + n0f) * 512 + (size_t)(tid + p * 256) * 8);
    };

    uint4 stA0 = fetchA(0 ^ phase);
    uint4 stA1 = fetchA(1 ^ phase);
    uint4 stB[4];
#pragma unroll
    for (int p = 0; p < 4; ++p) stB[p] = fetchB(0 ^ phase, p);

    f32x4 acc[4][4];
#pragma unroll
    for (int i = 0; i < 4; ++i)
#pragma unroll
      for (int j = 0; j < 4; ++j) acc[i][j] = (f32x4){0.f, 0.f, 0.f, 0.f};

#pragma unroll
    for (int ksi = 0; ksi < 8; ++ksi) {
      __syncthreads();
      lds4[tid] = ((ksi & 1) == 0) ? stA0 : stA1;
#pragma unroll
      for (int p = 0; p < 4; ++p) lds4[256 + tid + p * 256] = stB[p];
      if (ksi < 6) {
        int kf = (ksi + 2) ^ phase;
        if ((ksi & 1) == 0) stA0 = fetchA(kf); else stA1 = fetchA(kf);
      }
      if (ksi < 7) {
        int kf1 = (ksi + 1) ^ phase;
#pragma unroll
        for (int p = 0; p < 4; ++p) stB[p] = fetchB(kf1, p);
      }
      __syncthreads();
      bf16x8 a[4], b[4];
#pragma unroll
      for (int rf = 0; rf < 4; ++rf) a[rf] = *(const bf16x8*)&lds4[rf * 64 + lane];
#pragma unroll
      for (int cf = 0; cf < 4; ++cf) b[cf] = *(const bf16x8*)&lds4[256 + (wid * 4 + cf) * 64 + lane];
#pragma unroll
      for (int rf = 0; rf < 4; ++rf)
#pragma unroll
        for (int cf = 0; cf < 4; ++cf)
          acc[rf][cf] = __builtin_amdgcn_mfma_f32_16x16x32_bf16(a[rf], b[cf], acc[rf][cf], 0, 0, 0);
    }

    // quad-routed epilogue: y0 -> qf f32 | y1,y2 -> kvb bf16 | y3 -> sf f32
    bool bf16path;
    void* dstp_; int cstr_, dc0_, bcol0_;
    if (y == 0)      { bf16path = false; dstp_ = qf;  cstr_ = 256; dc0_ = 0;   bcol0_ = 0; }
    else if (y == 1) { bf16path = true;  dstp_ = kvb; cstr_ = 512; dc0_ = 0;   bcol0_ = 256; }
    else if (y == 2) { bf16path = true;  dstp_ = kvb; cstr_ = 512; dc0_ = 256; bcol0_ = 512; }
    else             { bf16path = false; dstp_ = sf;  cstr_ = 256; dc0_ = 0;   bcol0_ = 768; }
    const int fr0 = (lane >> 4) * 4;
    const int fc0 = lane & 15;
    if (!bf16path) {
      float* dst = (float*)dstp_;
      const int row0 = rt0 * 64 + fr0;
      const int cb2 = wid * 64 + fc0;
#pragma unroll
      for (int cf = 0; cf < 4; ++cf) {
        int c = cb2 + cf * 16;
        float bv = bcat1[bcol0_ + c];
#pragma unroll
        for (int rf = 0; rf < 4; ++rf) {
#pragma unroll
          for (int j = 0; j < 4; ++j) {
            int r = row0 + rf * 16 + j;
            if (r < N_NODES) dst[(size_t)r * cstr_ + c] = acc[rf][cf][j] + bv;
          }
        }
      }
    } else {
      __syncthreads();
      unsigned short* cl = (unsigned short*)ldsraw;   // [64][72]
      unsigned short* dst = (unsigned short*)dstp_;
      for (int pass = 0; pass < 4; ++pass) {
        if (wid == pass) {
#pragma unroll
          for (int cf = 0; cf < 4; ++cf) {
            int c = fc0 + cf * 16;
            float bv = bcat1[bcol0_ + pass * 64 + c];
#pragma unroll
            for (int rf = 0; rf < 4; ++rf)
#pragma unroll
              for (int j = 0; j < 4; ++j)
                cl[(fr0 + rf * 16 + j) * 72 + c] = f2bf(acc[rf][cf][j] + bv);
          }
        }
        __syncthreads();
#pragma unroll
        for (int id = tid; id < 512; id += 256) {
          int row = id >> 3, cc = (id & 7) * 8;
          int gr = rt0 * 64 + row;
          if (gr < N_NODES)
            *(uint4*)&dst[(size_t)gr * cstr_ + dc0_ + pass * 64 + cc] = *(const uint4*)&cl[row * 72 + cc];
        }
        __syncthreads();
      }
    }
  }
}

// ---------------- node2 GEMM: [N,256] @ [256,128] -> qkvs2 f32 ----------------
__global__ __launch_bounds__(256)
void gemm_node2(const unsigned short* __restrict__ ha, const unsigned short* __restrict__ W2f,
                const float* __restrict__ bcat2, float* __restrict__ qkvs2) {
  __shared__ uint4 lds4[1024];   // A 512 + B 512 chunks
  const int tid = threadIdx.x;
  const int wid = tid >> 6, lane = tid & 63;
  const int wr = wid >> 1, wc = wid & 1;
  const int rt0 = blockIdx.x * 2;
  const int phase = blockIdx.x & 7;

  auto fetchA = [&](int ks, int p) -> uint4 {
    int c = tid + p * 256;
    int rt = rt0 + (c >> 8);
    if (rt >= RT1) rt = RT1 - 1;
    return *(const uint4*)(ha + (size_t)rt * 16384 + (size_t)ks * 2048 + (size_t)(c & 255) * 8);
  };
  auto fetchB = [&](int ks, int p) -> uint4 {
    return *(const uint4*)(W2f + (size_t)ks * 8 * 512 + (size_t)(tid + p * 256) * 8);
  };

  uint4 stA0[2], stA1[2], stB[2];
#pragma unroll
  for (int p = 0; p < 2; ++p) stA0[p] = fetchA(0 ^ phase, p);
#pragma unroll
  for (int p = 0; p < 2; ++p) stA1[p] = fetchA(1 ^ phase, p);
#pragma unroll
  for (int p = 0; p < 2; ++p) stB[p] = fetchB(0 ^ phase, p);

  f32x4 acc[4][4];
#pragma unroll
  for (int i = 0; i < 4; ++i)
#pragma unroll
    for (int j = 0; j < 4; ++j) acc[i][j] = (f32x4){0.f, 0.f, 0.f, 0.f};

#pragma unroll
  for (int ksi = 0; ksi < 8; ++ksi) {
    __syncthreads();
#pragma unroll
    for (int p = 0; p < 2; ++p) lds4[tid + p * 256] = ((ksi & 1) == 0) ? stA0[p] : stA1[p];
#pragma unroll
    for (int p = 0; p < 2; ++p) lds4[512 + tid + p * 256] = stB[p];
    if (ksi < 6) {
      int kf = (ksi + 2) ^ phase;
      if ((ksi & 1) == 0) {
#pragma unroll
        for (int p = 0; p < 2; ++p) stA0[p] = fetchA(kf, p);
      } else {
#pragma unroll
        for (int p = 0; p < 2; ++p) stA1[p] = fetchA(kf, p);
      }
    }
    if (ksi < 7) {
      int kf1 = (ksi + 1) ^ phase;
#pragma unroll
      for (int p = 0; p < 2; ++p) stB[p] = fetchB(kf1, p);
    }
    __syncthreads();
    bf16x8 a[4], b[4];
#pragma unroll
    for (int rf = 0; rf < 4; ++rf) a[rf] = *(const bf16x8*)&lds4[(wr * 4 + rf) * 64 + lane];
#pragma unroll
    for (int cf = 0; cf < 4; ++cf) b[cf] = *(const bf16x8*)&lds4[512 + (wc * 4 + cf) * 64 + lane];
#pragma unroll
    for (int rf = 0; rf < 4; ++rf)
#pragma unroll
      for (int cf = 0; cf < 4; ++cf)
        acc[rf][cf] = __builtin_amdgcn_mfma_f32_16x16x32_bf16(a[rf], b[cf], acc[rf][cf], 0, 0, 0);
  }

  const int row0 = (rt0 + wr) * 64 + ((lane >> 4) * 4);
  const int cb2 = wc * 64 + (lane & 15);
#pragma unroll
  for (int cf = 0; cf < 4; ++cf) {
    int c = cb2 + cf * 16;
    float bv = bcat2[c];
#pragma unroll
    for (int rf = 0; rf < 4; ++rf) {
#pragma unroll
      for (int j = 0; j < 4; ++j) {
        int r = row0 + rf * 16 + j;
        if (r < N_NODES) qkvs2[(size_t)r * 128 + c] = acc[rf][cf][j] + bv;
      }
    }
  }
}

// ---------------- attention layer 1: 2-edge unroll, dual online state ----------------
__global__ __launch_bounds__(64)
void attn1_kernel(const float* __restrict__ qf, const unsigned short* __restrict__ kvb,
                  const float* __restrict__ sf, const unsigned short* __restrict__ e1b,
                  const int* __restrict__ srcs, const int* __restrict__ rowptr,
                  unsigned short* __restrict__ ha) {
  const int n = blockIdx.x;
  const int lane = threadIdx.x;
  const int h = lane >> 3;
  const int c0 = (lane & 7) * 4;
  const int off = h * 32 + c0;
  const int beg = rowptr[n], end = rowptr[n + 1];
  const float4 q = *(const float4*)&qf[(size_t)n * 256 + off];
  float m0 = -INFINITY, d0 = 0.f, x0 = 0.f, x1 = 0.f, x2 = 0.f, x3 = 0.f;
  float m1 = -INFINITY, d1 = 0.f, y0 = 0.f, y1 = 0.f, y2 = 0.f, y3 = 0.f;
  int i = beg;
  for (; i + 1 < end; i += 2) {
    const int sA = srcs[i], sB = srcs[i + 1];
    ushort4 evA = *(const ushort4*)&e1b[(size_t)i * 256 + off];
    ushort4 kkA = *(const ushort4*)&kvb[(size_t)sA * 512 + off];
    ushort4 vvA = *(const ushort4*)&kvb[(size_t)sA * 512 + 256 + off];
    ushort4 evB = *(const ushort4*)&e1b[(size_t)(i + 1) * 256 + off];
    ushort4 kkB = *(const ushort4*)&kvb[(size_t)sB * 512 + off];
    ushort4 vvB = *(const ushort4*)&kvb[(size_t)sB * 512 + 256 + off];
    float eA0=bf2f(evA.x), eA1=bf2f(evA.y), eA2=bf2f(evA.z), eA3=bf2f(evA.w);
    float eB0=bf2f(evB.x), eB1=bf2f(evB.y), eB2=bf2f(evB.z), eB3=bf2f(evB.w);
    float pA = q.x*(bf2f(kkA.x)+eA0) + q.y*(bf2f(kkA.y)+eA1) + q.z*(bf2f(kkA.z)+eA2) + q.w*(bf2f(kkA.w)+eA3);
    float pB = q.x*(bf2f(kkB.x)+eB0) + q.y*(bf2f(kkB.y)+eB1) + q.z*(bf2f(kkB.z)+eB2) + q.w*(bf2f(kkB.w)+eB3);
    pA += __shfl_xor(pA, 1); pA += __shfl_xor(pA, 2); pA += __shfl_xor(pA, 4);
    pB += __shfl_xor(pB, 1); pB += __shfl_xor(pB, 2); pB += __shfl_xor(pB, 4);
    pA *= 0.17677669529663687f;
    pB *= 0.17677669529663687f;
    {
      const float mn = fmaxf(m0, pA);
      const float sc = __expf(m0 - mn), w = __expf(pA - mn);
      d0 = d0 * sc + w;
      x0 = x0 * sc + w * (bf2f(vvA.x) + eA0);
      x1 = x1 * sc + w * (bf2f(vvA.y) + eA1);
      x2 = x2 * sc + w * (bf2f(vvA.z) + eA2);
      x3 = x3 * sc + w * (bf2f(vvA.w) + eA3);
      m0 = mn;
    }
    {
      const float mn = fmaxf(m1, pB);
      const float sc = __expf(m1 - mn), w = __expf(pB - mn);
      d1 = d1 * sc + w;
      y0 = y0 * sc + w * (bf2f(vvB.x) + eB0);
      y1 = y1 * sc + w * (bf2f(vvB.y) + eB1);
      y2 = y2 * sc + w * (bf2f(vvB.z) + eB2);
      y3 = y3 * sc + w * (bf2f(vvB.w) + eB3);
      m1 = mn;
    }
  }
  if (i < end) {
    const int sA = srcs[i];
    ushort4 evA = *(const ushort4*)&e1b[(size_t)i * 256 + off];
    ushort4 kkA = *(const ushort4*)&kvb[(size_t)sA * 512 + off];
    ushort4 vvA = *(const ushort4*)&kvb[(size_t)sA * 512 + 256 + off];
    float eA0=bf2f(evA.x), eA1=bf2f(evA.y), eA2=bf2f(evA.z), eA3=bf2f(evA.w);
    float pA = q.x*(bf2f(kkA.x)+eA0) + q.y*(bf2f(kkA.y)+eA1) + q.z*(bf2f(kkA.z)+eA2) + q.w*(bf2f(kkA.w)+eA3);
    pA += __shfl_xor(pA, 1); pA += __shfl_xor(pA, 2); pA += __shfl_xor(pA, 4);
    pA *= 0.17677669529663687f;
    const float mn = fmaxf(m0, pA);
    const float sc = __expf(m0 - mn), w = __expf(pA - mn);
    d0 = d0 * sc + w;
    x0 = x0 * sc + w * (bf2f(vvA.x) + eA0);
    x1 = x1 * sc + w * (bf2f(vvA.y) + eA1);
    x2 = x2 * sc + w * (bf2f(vvA.z) + eA2);
    x3 = x3 * sc + w * (bf2f(vvA.w) + eA3);
    m0 = mn;
  }
  float den = d0, a0 = x0, a1 = x1, a2 = x2, a3 = x3;
  if (m1 != -INFINITY) {   // merge dual states (state0 nonempty whenever state1 is)
    const float M = fmaxf(m0, m1);
    const float sA = __expf(m0 - M), sB = __expf(m1 - M);
    den = d0 * sA + d1 * sB;
    a0 = x0 * sA + y0 * sB; a1 = x1 * sA + y1 * sB;
    a2 = x2 * sA + y2 * sB; a3 = x3 * sA + y3 * sB;
  }
  const float inv = 1.f / (den + 1e-16f);
  const float4 sk = *(const float4*)&sf[(size_t)n * 256 + off];
  float o0 = fmaxf(a0 * inv + sk.x, 0.f);
  float o1 = fmaxf(a1 * inv + sk.y, 0.f);
  float o2 = fmaxf(a2 * inv + sk.z, 0.f);
  float o3 = fmaxf(a3 * inv + sk.w, 0.f);
  int rt = n >> 6, rf = (n >> 4) & 3, ir = n & 15;
  int kg = (lane & 7) >> 1, jj = 4 * (lane & 1);
  ushort4 w4;
  w4.x = f2bf(o0); w4.y = f2bf(o1); w4.z = f2bf(o2); w4.w = f2bf(o3);
  *(ushort4*)&ha[(size_t)rt * 16384 + h * 2048 + rf * 512 + (ir + 16 * kg) * 8 + jj] = w4;
}

// ---------------- attention layer 2: 2-edge unroll ----------------
__global__ __launch_bounds__(64)
void attn2_kernel(const float* __restrict__ qkvs2, const unsigned short* __restrict__ e2b,
                  const int* __restrict__ srcs, const int* __restrict__ rowptr,
                  float* __restrict__ outp) {
  const int n = blockIdx.x;
  const int tid = threadIdx.x;
  const int c = tid & 31;
  const int beg = rowptr[n], end = rowptr[n + 1];
  const float qv = qkvs2[(size_t)n * 128 + c];
  float m0 = -INFINITY, d0 = 0.f, x0 = 0.f;
  float m1 = -INFINITY, d1 = 0.f, y0 = 0.f;
  int i = beg;
  for (; i + 1 < end; i += 2) {
    const int sA = srcs[i], sB = srcs[i + 1];
    const float eA = bf2f(e2b[(size_t)i * 32 + c]);
    const float eB = bf2f(e2b[(size_t)(i + 1) * 32 + c]);
    float pA = qv * (qkvs2[(size_t)sA * 128 + 32 + c] + eA);
    float pB = qv * (qkvs2[(size_t)sB * 128 + 32 + c] + eB);
    const float vA = qkvs2[(size_t)sA * 128 + 64 + c] + eA;
    const float vB = qkvs2[(size_t)sB * 128 + 64 + c] + eB;
#pragma unroll
    for (int off = 16; off; off >>= 1) pA += __shfl_xor(pA, off);
#pragma unroll
    for (int off = 16; off; off >>= 1) pB += __shfl_xor(pB, off);
    pA *= 0.17677669529663687f;
    pB *= 0.17677669529663687f;
    {
      const float mn = fmaxf(m0, pA);
      const float sc = __expf(m0 - mn), w = __expf(pA - mn);
      d0 = d0 * sc + w; x0 = x0 * sc + w * vA; m0 = mn;
    }
    {
      const float mn = fmaxf(m1, pB);
      const float sc = __expf(m1 - mn), w = __expf(pB - mn);
      d1 = d1 * sc + w; y0 = y0 * sc + w * vB; m1 = mn;
    }
  }
  if (i < end) {
    const int sA = srcs[i];
    const float eA = bf2f(e2b[(size_t)i * 32 + c]);
    float pA = qv * (qkvs2[(size_t)sA * 128 + 32 + c] + eA);
    const float vA = qkvs2[(size_t)sA * 128 + 64 + c] + eA;
#pragma unroll
    for (int off = 16; off; off >>= 1) pA += __shfl_xor(pA, off);
    pA *= 0.17677669529663687f;
    const float mn = fmaxf(m0, pA);
    const float sc = __expf(m0 - mn), w = __expf(pA - mn);
    d0 = d0 * sc + w; x0 = x0 * sc + w * vA; m0 = mn;
  }
  float den = d0, acc = x0;
  if (m1 != -INFINITY) {
    const float M = fmaxf(m0, m1);
    const float sA = __expf(m0 - M), sB = __expf(m1 - M);
    den = d0 * sA + d1 * sB;
    acc = x0 * sA + y0 * sB;
  }
  if (tid < 32) {
    float o = acc / (den + 1e-16f) + qkvs2[(size_t)n * 128 + 96 + c];
    outp[(size_t)n * 32 + c] = fmaxf(o, 0.f);
  }
}

// ---------------- launcher ----------------
extern "C" void kernel_launch(void* const* d_in, const int* in_sizes, int n_in,
                              void* d_out, int out_size, void* d_ws, size_t ws_size,
                              hipStream_t stream) {
  const float* x   = (const float*)d_in[0];
  const float* lu  = (const float*)d_in[1];
  const int*   ei  = (const int*)d_in[2];
  const float* tt  = (const float*)d_in[3];
  const float* msg = (const float*)d_in[4];
  const float* tw  = (const float*)d_in[5];
  const float* tb  = (const float*)d_in[6];
  const float* Wq1 = (const float*)d_in[7];  const float* bq1 = (const float*)d_in[8];
  const float* Wk1 = (const float*)d_in[9];  const float* bk1 = (const float*)d_in[10];
  const float* Wv1 = (const float*)d_in[11]; const float* bv1 = (const float*)d_in[12];
  const float* We1 = (const float*)d_in[13];
  const float* Ws1 = (const float*)d_in[14]; const float* bs1 = (const float*)d_in[15];
  const float* Wq2 = (const float*)d_in[16]; const float* bq2 = (const float*)d_in[17];
  const float* Wk2 = (const float*)d_in[18]; const float* bk2 = (const float*)d_in[19];
  const float* Wv2 = (const float*)d_in[20]; const float* bv2 = (const float*)d_in[21];
  const float* We2 = (const float*)d_in[22];
  const float* Ws2 = (const float*)d_in[23]; const float* bs2 = (const float*)d_in[24];

  const int* srcp = ei;
  const int* dstp = ei + N_EDGES;

  char* p = (char*)d_ws;
  auto alloc = [&](size_t bytes) -> char* {
    char* r = p;
    p += (bytes + 255) & ~(size_t)255;
    return r;
  };
  int*   deg     = (int*)alloc((size_t)N_NODES * 4);
  int*   fill    = (int*)alloc((size_t)N_NODES * 4);
  int*   rowptr  = (int*)alloc((size_t)(N_NODES + 1) * 4);
  int*   sortpos = (int*)alloc((size_t)N_EDGES * 4);
  int*   srcs    = (int*)alloc((size_t)N_EDGES * 4);
  float* rel     = (float*)alloc((size_t)N_EDGES * 4);
  unsigned short* xa   = (unsigned short*)alloc((size_t)RT1 * 32768);
  unsigned short* W1f  = (unsigned short*)alloc((size_t)8 * 64 * 1024);
  unsigned short* We1f = (unsigned short*)alloc((size_t)8 * 16 * 1024);
  unsigned short* W2f  = (unsigned short*)alloc((size_t)8 * 8 * 1024);
  unsigned short* We2f = (unsigned short*)alloc((size_t)8 * 4 * 1024);
  float* bcat1  = (float*)alloc(1024 * 4);
  float* bcat2  = (float*)alloc(128 * 4);
  float* qf     = (float*)alloc((size_t)N_NODES * 256 * 4);
  unsigned short* kvb = (unsigned short*)alloc((size_t)N_NODES * 512 * 2);
  float* sf     = (float*)alloc((size_t)N_NODES * 256 * 4);
  unsigned short* e1b = (unsigned short*)alloc((size_t)N_EDGES * 256 * 2);   // 82 MB
  unsigned short* ha  = (unsigned short*)alloc((size_t)RT1 * 32768);
  float* qkvs2  = (float*)alloc((size_t)N_NODES * 128 * 4);
  unsigned short* e2b = (unsigned short*)alloc((size_t)N_EDGES * 32 * 2);
  float* outp   = (float*)d_out;

  hipMemsetAsync(deg, 0, (size_t)N_NODES * 4, stream);
  hipMemsetAsync(fill, 0, (size_t)N_NODES * 4, stream);
  hipMemsetAsync(ha + (size_t)(RT1 - 1) * 16384, 0, 32768, stream);  // zero pad rows 10000-10047

  prep1_kernel<<<625, 256, 0, stream>>>(lu, srcp, dstp, tt, rel, deg, N_EDGES);
  scan_kernel<<<1, 1024, 0, stream>>>(deg, rowptr, N_NODES);
  scatter_kernel<<<625, 256, 0, stream>>>(srcp, dstp, rowptr, fill, sortpos, srcs, N_EDGES);

  conv_all_kernel<<<ceildiv(CONVX_T + 369792, 256), 256, 0, stream>>>(
      x, xa, Wq1, Wk1, Wv1, Ws1, We1, Wq2, Wk2, Wv2, Ws2, We2,
      bq1, bk1, bv1, bs1, bq2, bk2, bv2, bs2,
      W1f, We1f, W2f, We2f, bcat1, bcat2);

  // merged: 2500 edge blocks (e1+e2) + 628 node1 blocks
  big_gemm<<<RTE + RT1 * 4, 256, 0, stream>>>(
      xa, W1f, bcat1, qf, kvb, sf, We1f, We2f, e1b, e2b,
      rel, tw, tb, msg, sortpos);

  attn1_kernel<<<N_NODES, 64, 0, stream>>>(qf, kvb, sf, e1b, srcs, rowptr, ha);
  gemm_node2<<<ceildiv(RT1, 2), 256, 0, stream>>>(ha, W2f, bcat2, qkvs2);
  attn2_kernel<<<N_NODES, 64, 0, stream>>>(qkvs2, e2b, srcs, rowptr, outp);
}